// Round 10
// baseline (582.265 us; speedup 1.0000x reference)
//
#include <hip/hip_runtime.h>
#include <stdint.h>

// DoomLiquidNet: conv(3->32,k4s2p1) -> conv(32->64,k4s2p1) -> CfC core -> logits
// Inputs f32 (detected on device; bf16 fallback kept). Compute in bf16 MFMA.
//
// R16 = R15 resubmit (R15 bench was an infra failure: container died twice,
//   no counters; kernel re-audited - all LDS/global accesses in bounds, same
//   flake pattern as R8->R9 and R12->R13 which cleared on resubmit).
// R15 = R14 (421us total, k_convs 124us) + conflict-free LDS strides.
//   R14 counters: BANK_CONFLICT 7.3M->19.9M; conv2 = 512 ds_read_b32/wave,
//   quad bank bases {0,4,4,8} (plane delta 612 === 2-row delta 36 === 4 mod 32)
//   -> 4-way conflict on banks 8-15; ~LDS-serialization critical path.
//   Fix: pad PLANE strides (row-level padding can't separate quads 1/2):
//     A1H co-stride 612 -> 624 (===16 mod 32), XS plane 2244 -> 2256 (===16)
//   -> read bases {0,4,16,20}: exact 2-way tiling = free (m136).
//   Writes go 4->8-way but are 64 instrs vs 512 reads -> net ~-1.5K cyc/wave.
//   LDS 66368 -> 67280 B, still 2 blk/CU. Data mapping identical to R14.
//
// ws layout:
//   xbp   : f32  [16][2048][128]     @ 0           16777216 B
//   feats : bf16 [2048][16384]       @ 150994944   67108864 B
//   bbT   : bf16 [128][16448]        @ 218103808    4210688 B
//   HT    : bf16 [256][128]          @ 222314496      65536 B
//   w1p   : bf16 [32][64]            @ 222380032       4096 B
//   w2c   : bf16 [64][512]           @ 222384128      65536 B
//   xb    : f32  [2048][128]         @ 222449664    1048576 B
//   rout  : f32  [2048][64]          @ 223498240     524288 B
//   consts: f32  [3048]              @ 224022528      12288 B
//   flag  : int                      @ 224034816          4 B

typedef unsigned short u16;
typedef unsigned int u32;

typedef float f32x4 __attribute__((ext_vector_type(4)));
typedef short s16x8 __attribute__((ext_vector_type(8)));
typedef __bf16 b16x8 __attribute__((ext_vector_type(8)));

template <typename V>
__device__ inline auto mfma_sel(V a, V b, f32x4 c, int)
    -> decltype(__builtin_amdgcn_mfma_f32_16x16x32_bf16(a, b, c, 0, 0, 0)) {
  return __builtin_amdgcn_mfma_f32_16x16x32_bf16(a, b, c, 0, 0, 0);
}
template <typename V>
__device__ inline f32x4 mfma_sel(V a, V b, f32x4 c, long) {
  union UU { V s; b16x8 b; };
  UU ua; ua.s = a;
  UU ub; ub.s = b;
  return __builtin_amdgcn_mfma_f32_16x16x32_bf16(ua.b, ub.b, c, 0, 0, 0);
}
__device__ inline f32x4 mfma16x16x32(s16x8 a, s16x8 b, f32x4 c) {
  return mfma_sel(a, b, c, 0);
}

__device__ inline float bf2f(u16 v) {
  union { u32 i; float f; } x; x.i = ((u32)v) << 16; return x.f;
}
__device__ inline u16 f2bf(float f) {  // round-to-nearest-even
  union { float f; u32 i; } x; x.f = f;
  u32 i = x.i;
  i += 0x7fffu + ((i >> 16) & 1u);
  return (u16)(i >> 16);
}
__device__ inline void bf2x2(u32 u, float& lo, float& hi) {
  union { u32 i; float f; } a, b;
  a.i = u << 16; b.i = u & 0xffff0000u;
  lo = a.f; hi = b.f;
}
__device__ inline float ldf(int isbf, const void* p, size_t i) {
  return isbf ? bf2f(((const u16*)p)[i]) : ((const float*)p)[i];
}
__device__ inline u16 ldb(int isbf, const void* p, size_t i) {
  return isbf ? ((const u16*)p)[i] : f2bf(((const float*)p)[i]);
}
__device__ inline float fast_tanh(float x) {
  float ax = fabsf(x);
  float e = __expf(2.0f * ax);
  float t = 1.0f - 2.0f / (e + 1.0f);
  return copysignf(t, x);
}

// ---------- fused prep: detect + consts + w1p + w2c + bbT + HT ----------
__global__ __launch_bounds__(256)
void k_prep_all(const u32* __restrict__ bwords,
                const void* b1, const void* b2, const void* bbb,
                const void* f1b, const void* f2b, const void* tab,
                const void* tbb, const void* oww, const void* obb,
                const void* hx, const void* w1, const void* w2,
                const void* bw, const void* f1w, const void* f2w,
                const void* taw, const void* tbw,
                float* __restrict__ consts, u16* __restrict__ w1p,
                u16* __restrict__ w2c, u16* __restrict__ bbT,
                u16* __restrict__ HT, int* __restrict__ flag) {
  __shared__ u16 t[64][65];
  const int tid = threadIdx.x;
  const int b = blockIdx.x;
  const u32 wd = bwords[tid & 63];
  const u32 ex = (wd >> 7) & 0xFFu;
  unsigned long long m = __ballot(ex >= 100u && ex <= 126u);
  const int isbf = (__popcll(m) >= 32) ? 1 : 0;
  if (b == 0 && tid == 0) *flag = isbf;

  if (b < 12) {
    const int e = b * 256 + tid;
    if (e >= 3048) return;
    float v;
    if (e < 32)        v = ldf(isbf, b1, e);
    else if (e < 96)   v = ldf(isbf, b2, e - 32);
    else if (e < 224)  v = ldf(isbf, bbb, e - 96);
    else if (e < 288)  v = ldf(isbf, f1b, e - 224);
    else if (e < 352)  v = ldf(isbf, f2b, e - 288);
    else if (e < 416)  v = ldf(isbf, tab, e - 352);
    else if (e < 480)  v = ldf(isbf, tbb, e - 416);
    else if (e < 992)  v = ldf(isbf, oww, e - 480);
    else if (e < 1000) v = ldf(isbf, obb, e - 992);
    else               v = ldf(isbf, hx, e - 1000);
    consts[e] = v;
  } else if (b < 20) {
    const int e = (b - 12) * 256 + tid;
    const int k = e & 63, co = e >> 6;
    w1p[e] = (k < 48) ? ldb(isbf, w1, co * 48 + k) : (u16)0;
  } else if (b < 148) {
    const int e = (b - 20) * 256 + tid;
    w2c[e] = ldb(isbf, w2, e);
  } else if (b < 662) {
    const int idx = b - 148;
    const int k0 = (idx >> 1) * 64, j0 = (idx & 1) * 64;
    #pragma unroll
    for (int i = 0; i < 16; ++i) {
      int e = tid + 256 * i;
      int kl = e >> 6, jl = e & 63;
      t[kl][jl] = ldb(isbf, bw, (size_t)(k0 + kl) * 128 + j0 + jl);
    }
    __syncthreads();
    #pragma unroll
    for (int i = 0; i < 16; ++i) {
      int e = tid + 256 * i;
      int jl = e >> 6, kl = e & 63;
      bbT[(size_t)(j0 + jl) * 16448 + k0 + kl] = t[kl][jl];
    }
  } else {
    const int idx = b - 662;
    const int h = idx >> 1, i0 = (idx & 1) * 64;
    const void* W = (h == 0) ? f1w : (h == 1) ? f2w : (h == 2) ? taw : tbw;
    #pragma unroll
    for (int i = 0; i < 16; ++i) {
      int e = tid + 256 * i;
      int il = e >> 6, cl = e & 63;
      t[il][cl] = ldb(isbf, W, (i0 + il) * 64 + cl);
    }
    __syncthreads();
    #pragma unroll
    for (int i = 0; i < 16; ++i) {
      int e = tid + 256 * i;
      int cl = e >> 6, il = e & 63;
      HT[(h * 64 + cl) * 128 + i0 + il] = t[il][cl];
    }
  }
}

// ---------- fused conv1+conv2: one image per block (R14 + strides) ----------
// LDS u32 map (conflict-free plane strides):
//   XS   @ 0     : 3 planes x (66 rows x 34 u32, stride 2256) rows 0/65 = 0
//   ZS   @ 6768  : 68 u32 zeros (conv1 K-pad plane reads)
//   A1H  @ 6836  : 16 planes (stride 624 = 34 rows x 18 u32 + 12 pad)
//   total 16820 u32 = 67280 B  -> 2 blocks/CU
__global__ __launch_bounds__(512, 4)
void k_convs(const int* __restrict__ flagp, const void* __restrict__ x,
             const u16* __restrict__ w1p, const u16* __restrict__ w2c,
             const float* __restrict__ consts, u16* __restrict__ feats) {
  __shared__ u32 lx[16820];
  const int isbf = *flagp;
  const int n = blockIdx.x;
  const int tid = threadIdx.x;
  const int wv = tid >> 6, lane = tid & 63, quad = lane >> 4, l15 = lane & 15;

  // zero: xs border rows (204) + zero strip (68) + whole a1h (9984)
  for (int e = tid; e < 10256; e += 512) {
    int idx;
    if (e < 204) {
      const int pl = e / 68;
      const int rem = e - pl * 68;
      const int r = rem / 34;
      idx = pl * 2256 + r * (65 * 34) + (rem - r * 34);
    } else if (e < 272) {
      idx = 6768 + (e - 204);
    } else {
      idx = 6836 + (e - 272);
    }
    lx[idx] = 0u;
  }
  // stage x -> XS (interior rows 1..64), shifted-pair bf16
  for (int e = tid; e < 3072; e += 512) {
    const int ci = e >> 10;
    const int rr = (e >> 4) & 63;
    const int tt = e & 15;
    u32* dst = &lx[ci * 2256 + (rr + 1) * 34];
    if (!isbf) {
      const float* src = (const float*)x + (((size_t)n * 3 + ci) * 64 + rr) * 64 + 4 * tt;
      const f32x4 v = *(const f32x4*)src;
      const float pv = tt ? src[-1] : 0.f;
      dst[2 * tt]     = (u32)f2bf(pv)   | (((u32)f2bf(v[0])) << 16);
      dst[2 * tt + 1] = (u32)f2bf(v[1]) | (((u32)f2bf(v[2])) << 16);
      if (tt == 15) { dst[32] = (u32)f2bf(v[3]); dst[33] = 0u; }
    } else {
      const u16* src = (const u16*)x + (((size_t)n * 3 + ci) * 64 + rr) * 64 + 4 * tt;
      const u16 pv = tt ? src[-1] : (u16)0;
      dst[2 * tt]     = (u32)pv | (((u32)src[0]) << 16);
      dst[2 * tt + 1] = (u32)src[1] | (((u32)src[2]) << 16);
      if (tt == 15) { dst[32] = (u32)src[3]; dst[33] = 0u; }
    }
  }
  __syncthreads();

  f32x4 acc2[8];
  #pragma unroll
  for (int rr = 0; rr < 8; ++rr) acc2[rr] = f32x4{0.f, 0.f, 0.f, 0.f};

  const int khb = (quad & 1) * 2;
  const int cih = quad >> 1;
  const int mt = wv & 3;    // conv2: co-group
  const int og = wv >> 2;   // conv2: oh-octet (oh = og*8 + rr)
  u16* lp = (u16*)lx;

  #pragma unroll
  for (int h = 0; h < 2; ++h) {
    // ---- conv1 half: co = h*16 .. h*16+15 -> A1H ----
    const s16x8 af0 = *(const s16x8*)(w1p + (h * 16 + l15) * 64 + quad * 8);
    const s16x8 af1 = *(const s16x8*)(w1p + (h * 16 + l15) * 64 + 32 + quad * 8);
    #pragma unroll
    for (int i = 0; i < 8; ++i) {
      const int nt = wv * 8 + i;
      const int oh = nt >> 1;
      const int ob = (nt & 1) * 16;
      f32x4 a1acc = f32x4{0.f, 0.f, 0.f, 0.f};
      {
        const int base = cih * 2256 + (2 * oh + khb) * 34 + ob + l15;
        union { u32 u[4]; s16x8 v; } bf;
        bf.u[0] = lx[base];
        bf.u[1] = lx[base + 1];
        bf.u[2] = lx[base + 34];
        bf.u[3] = lx[base + 35];
        a1acc = mfma16x16x32(af0, bf.v, a1acc);
      }
      {
        // ci1 = 2+cih: plane 2 real, plane 3 = K-pad -> zero strip
        const int base = (cih == 0) ? (2 * 2256 + (2 * oh + khb) * 34 + ob + l15)
                                    : (6768 + ob + l15);
        union { u32 u[4]; s16x8 v; } bf;
        bf.u[0] = lx[base];
        bf.u[1] = lx[base + 1];
        bf.u[2] = lx[base + 34];
        bf.u[3] = lx[base + 35];
        a1acc = mfma16x16x32(af1, bf.v, a1acc);
      }
      #pragma unroll
      for (int r = 0; r < 4; ++r) {
        const int co = quad * 4 + r;
        float v = a1acc[r] + consts[h * 16 + co];
        v = v > 0.f ? v : 0.f;
        lp[(6836 + co * 624 + (oh + 1) * 18) * 2 + ob + l15 + 1] = f2bf(v);
      }
    }
    __syncthreads();  // a1 half ready
    // ---- conv2 K-half: planes 16h..16h+15 ----
    // wave remap (R14): ONE w2c fragment per kst, 8 MFMA vs a1 rows.
    #pragma unroll
    for (int kst = 0; kst < 8; ++kst) {
      const int kglob = h * 8 + kst;
      const s16x8 afr =
          *(const s16x8*)(w2c + (mt * 16 + l15) * 512 + kglob * 32 + quad * 8);
      const int ci = kst * 2 + cih;
      #pragma unroll
      for (int rr = 0; rr < 8; ++rr) {
        const int row1 = 2 * (og * 8 + rr) + khb;
        const int base = 6836 + ci * 624 + row1 * 18 + l15;
        union { u32 u[4]; s16x8 v; } bf;
        bf.u[0] = lx[base];
        bf.u[1] = lx[base + 1];
        bf.u[2] = lx[base + 18];
        bf.u[3] = lx[base + 19];
        acc2[rr] = mfma16x16x32(afr, bf.v, acc2[rr]);
      }
    }
    if (h == 0) __syncthreads();  // conv2 h0 done reading before conv1 h1 writes
  }
  // ---- epilogue: feats ----
  #pragma unroll
  for (int rr = 0; rr < 8; ++rr) {
    const int oh = og * 8 + rr;
    #pragma unroll
    for (int r = 0; r < 4; ++r) {
      const int co = mt * 16 + quad * 4 + r;
      const float bias = consts[32 + co];
      float v = acc2[rr][r] + bias;
      v = v > 0.f ? v : 0.f;
      feats[(size_t)n * 16384 + co * 256 + oh * 16 + l15] = f2bf(v);
    }
  }
}

// ---------- xb partials: feats @ bb_w[:16384], split-K=16, NO atomics ------
__global__ __launch_bounds__(256)
void k_xb(const u16* __restrict__ feats, const u16* __restrict__ bbT,
          float* __restrict__ xbp) {
  const int m0 = blockIdx.x * 64;
  const int kc = blockIdx.y;
  const int kc0 = kc * 1024;
  const int tid = threadIdx.x;
  const int w = tid >> 6, lane = tid & 63, quad = lane >> 4, l15 = lane & 15;
  f32x4 acc[4][2];
  #pragma unroll
  for (int mt = 0; mt < 4; ++mt)
    #pragma unroll
    for (int i = 0; i < 2; ++i) acc[mt][i] = f32x4{0.f, 0.f, 0.f, 0.f};
  #pragma unroll 4
  for (int kst = 0; kst < 32; ++kst) {
    const int k = kc0 + kst * 32 + quad * 8;
    s16x8 afrag[4], bfrag[2];
    #pragma unroll
    for (int mt = 0; mt < 4; ++mt)
      afrag[mt] = *(const s16x8*)(feats + (size_t)(m0 + mt * 16 + l15) * 16384 + k);
    #pragma unroll
    for (int i = 0; i < 2; ++i)
      bfrag[i] = *(const s16x8*)(bbT + (size_t)((w * 2 + i) * 16 + l15) * 16448 + k);
    #pragma unroll
    for (int mt = 0; mt < 4; ++mt)
      #pragma unroll
      for (int i = 0; i < 2; ++i)
        acc[mt][i] = mfma16x16x32(afrag[mt], bfrag[i], acc[mt][i]);
  }
  float* dst = xbp + (size_t)kc * 262144;
  #pragma unroll
  for (int mt = 0; mt < 4; ++mt)
    #pragma unroll
    for (int i = 0; i < 2; ++i) {
      const int j = (w * 2 + i) * 16 + l15;
      #pragma unroll
      for (int r = 0; r < 4; ++r) {
        const int m = m0 + mt * 16 + quad * 4 + r;
        dst[m * 128 + j] = acc[mt][i][r];
      }
    }
}

// ---------- reduce split-K partials -> xb ----------
__global__ __launch_bounds__(256)
void k_xbsum(const float* __restrict__ xbp, float* __restrict__ xb) {
  const int e = blockIdx.x * 256 + threadIdx.x;
  float s = 0.f;
  #pragma unroll
  for (int kc = 0; kc < 16; ++kc) s += xbp[(size_t)kc * 262144 + e];
  xb[e] = s;
}

// ---------- CfC recurrence: one block per batch row, 3 barriers/step ----------
__global__ __launch_bounds__(256)
void k_rec(const int* __restrict__ flagp, const float* __restrict__ xb,
           const u16* __restrict__ bbT, const u16* __restrict__ HT,
           const float* __restrict__ consts, float* __restrict__ rout,
           void* __restrict__ outv) {
  __shared__ float xbl[64 * 128];
  __shared__ float h[64];
  __shared__ float bbv[128];
  __shared__ float heads[256];
  const int isbf = *flagp;
  const int b = blockIdx.x;
  const int tid = threadIdx.x;
  {
    const float* src = xb + (size_t)b * 64 * 128;
    #pragma unroll
    for (int q = 0; q < 32; ++q) xbl[q * 256 + tid] = src[q * 256 + tid];
  }
  // phase-1 weights: full K=64 column for j = tid (threads 0..127)
  float w1r[64];
  if (tid < 128) {
    const u32* src = (const u32*)(bbT + (size_t)tid * 16448 + 16384);
    #pragma unroll
    for (int q = 0; q < 32; ++q) bf2x2(src[q], w1r[2 * q], w1r[2 * q + 1]);
  }
  float w2r[128];
  {
    const u32* src = (const u32*)(HT + tid * 128);
    #pragma unroll
    for (int q = 0; q < 64; ++q) bf2x2(src[q], w2r[2 * q], w2r[2 * q + 1]);
  }
  const float hbias = consts[224 + tid];
  const float bbias = (tid < 128) ? consts[96 + tid] : 0.f;
  if (tid < 64) h[tid] = consts[1000 + b * 64 + tid];
  __syncthreads();
  for (int t = 0; t < 64; ++t) {
    if (tid < 128) {
      float p0 = 0.f, p1 = 0.f, p2 = 0.f, p3 = 0.f;
      #pragma unroll
      for (int q = 0; q < 16; ++q) {
        p0 += h[4 * q + 0] * w1r[4 * q + 0];
        p1 += h[4 * q + 1] * w1r[4 * q + 1];
        p2 += h[4 * q + 2] * w1r[4 * q + 2];
        p3 += h[4 * q + 3] * w1r[4 * q + 3];
      }
      const float s = (p0 + p1) + (p2 + p3) + xbl[t * 128 + tid] + bbias;
      bbv[tid] = 1.7159f * fast_tanh(0.666f * s);
    }
    __syncthreads();
    float c0 = 0.f, c1 = 0.f, c2 = 0.f, c3 = 0.f;
    #pragma unroll
    for (int q = 0; q < 32; ++q) {
      c0 += bbv[4 * q + 0] * w2r[4 * q + 0];
      c1 += bbv[4 * q + 1] * w2r[4 * q + 1];
      c2 += bbv[4 * q + 2] * w2r[4 * q + 2];
      c3 += bbv[4 * q + 3] * w2r[4 * q + 3];
    }
    heads[tid] = (c0 + c1) + (c2 + c3) + hbias;
    __syncthreads();
    if (tid < 64) {
      const float ff1 = fast_tanh(heads[tid]);
      const float ff2 = fast_tanh(heads[64 + tid]);
      const float ti = 1.f / (1.f + __expf(-(heads[128 + tid] + heads[192 + tid])));
      const float hn = ff1 * (1.f - ti) + ti * ff2;
      h[tid] = hn;
      rout[((size_t)b * 64 + t) * 64 + tid] = hn;
    }
    __syncthreads();
  }
  if (tid < 64) {
    if (isbf) ((u16*)outv)[16384 + b * 64 + tid] = f2bf(h[tid]);
    else      ((float*)outv)[16384 + b * 64 + tid] = h[tid];
  }
}

// ---------- logits = rout @ out_w + out_b ----------
__global__ __launch_bounds__(256)
void k_logits(const int* __restrict__ flagp, const float* __restrict__ rout,
              const float* __restrict__ consts, void* __restrict__ outv) {
  __shared__ float W[512];
  __shared__ float Bv[8];
  const int isbf = *flagp;
  const int tid = threadIdx.x;
  for (int e = tid; e < 512; e += 256) W[e] = consts[480 + e];
  if (tid < 8) Bv[tid] = consts[992 + tid];
  __syncthreads();
  const int bt = blockIdx.x * 256 + tid;
  float acc[8];
  #pragma unroll
  for (int c = 0; c < 8; ++c) acc[c] = Bv[c];
  const f32x4* r = (const f32x4*)(rout + (size_t)bt * 64);
  #pragma unroll
  for (int q = 0; q < 16; ++q) {
    f32x4 v = r[q];
    #pragma unroll
    for (int u = 0; u < 4; ++u) {
      const float rv = v[u];
      const int i = 4 * q + u;
      #pragma unroll
      for (int c = 0; c < 8; ++c) acc[c] += rv * W[i * 8 + c];
    }
  }
  if (isbf) {
    u32 pk[4];
    #pragma unroll
    for (int c = 0; c < 4; ++c)
      pk[c] = (u32)f2bf(acc[2 * c]) | ((u32)f2bf(acc[2 * c + 1]) << 16);
    *(uint4*)((u16*)outv + (size_t)bt * 8) = *(const uint4*)pk;
  } else {
    float* o = (float*)outv + (size_t)bt * 8;
    *(f32x4*)o = f32x4{acc[0], acc[1], acc[2], acc[3]};
    *(f32x4*)(o + 4) = f32x4{acc[4], acc[5], acc[6], acc[7]};
  }
}

extern "C" void kernel_launch(void* const* d_in, const int* in_sizes, int n_in,
                              void* d_out, int out_size, void* d_ws, size_t ws_size,
                              hipStream_t stream) {
  const void* x   = d_in[0];
  const void* hx  = d_in[1];
  const void* w1  = d_in[2];
  const void* b1  = d_in[3];
  const void* w2  = d_in[4];
  const void* b2  = d_in[5];
  const void* bbw = d_in[6];
  const void* bbb = d_in[7];
  const void* f1w = d_in[8];
  const void* f1b = d_in[9];
  const void* f2w = d_in[10];
  const void* f2b = d_in[11];
  const void* taw = d_in[12];
  const void* tab = d_in[13];
  const void* tbw = d_in[14];
  const void* tbb = d_in[15];
  const void* oww = d_in[16];
  const void* obb = d_in[17];

  char* ws = (char*)d_ws;
  float* xbp   = (float*)(ws);
  u16*   feats = (u16*)(ws + 150994944);
  u16*   bbT   = (u16*)(ws + 218103808);
  u16*   HT    = (u16*)(ws + 222314496);
  u16*   w1p   = (u16*)(ws + 222380032);
  u16*   w2c   = (u16*)(ws + 222384128);
  float* xb    = (float*)(ws + 222449664);
  float* rout  = (float*)(ws + 223498240);
  float* consts= (float*)(ws + 224022528);
  int*   flag  = (int*)(ws + 224034816);

  k_prep_all<<<670, 256, 0, stream>>>((const u32*)bbw, b1, b2, bbb, f1b, f2b,
                                      tab, tbb, oww, obb, hx, w1, w2, bbw,
                                      f1w, f2w, taw, tbw,
                                      consts, w1p, w2c, bbT, HT, flag);
  k_convs<<<2048, 512, 0, stream>>>(flag, x, w1p, w2c, consts, feats);
  k_xb<<<dim3(32, 16), 256, 0, stream>>>(feats, bbT, xbp);
  k_xbsum<<<1024, 256, 0, stream>>>(xbp, xb);
  k_rec<<<32, 256, 0, stream>>>(flag, xb, bbT, HT, consts, rout, d_out);
  k_logits<<<8, 256, 0, stream>>>(flag, rout, consts, d_out);
}

// Round 11
// 468.759 us; speedup vs baseline: 1.2421x; 1.2421x over previous
//
#include <hip/hip_runtime.h>
#include <stdint.h>

// DoomLiquidNet: conv(3->32,k4s2p1) -> conv(32->64,k4s2p1) -> CfC core -> logits
// Inputs f32 (detected on device; bf16 fallback kept). Compute in bf16 MFMA.
//
// R17 = R15/R16 strides + launch_bounds(512,4)->(512,2).
//   R16 post-mortem: conflict-free strides raised VGPR demand past the
//   (512,4) cap of 64 (VGPR_Count pinned at 64, WRITE 65->520MB spill,
//   k_convs 310us). Cap law for 512-thr blocks: alloc_cap = 256/N
//   (N=4->64 R16, N=6->40 R11, N=8->32 R7). (512,2) -> cap 128 >= demand
//   ~70 -> no spill. Residency unchanged: ~70 VGPR -> 16 waves/CU limit
//   == LDS limit (67.3KB -> 2 blk x 8 waves) == R14's proven regime.
// R15 strides: A1H co-stride 612->624 (===16 mod 32), XS plane 2244->2256
//   -> conv2 quad read bases {0,4,16,20} = exact 2-way bank tiling (free,
//   m136) vs R14's 4-way on banks 8-15 (BANK_CONFLICT 19.9M).
// R14: conv2 wave remap (mt=wv&3, og=wv>>2): ONE w2c fragment/kst x 8 MFMA;
//   per-wave w2c traffic 64KB->16KB -> k_convs 193->124us, total 421us.
//
// ws layout:
//   xbp   : f32  [16][2048][128]     @ 0           16777216 B
//   feats : bf16 [2048][16384]       @ 150994944   67108864 B
//   bbT   : bf16 [128][16448]        @ 218103808    4210688 B
//   HT    : bf16 [256][128]          @ 222314496      65536 B
//   w1p   : bf16 [32][64]            @ 222380032       4096 B
//   w2c   : bf16 [64][512]           @ 222384128      65536 B
//   xb    : f32  [2048][128]         @ 222449664    1048576 B
//   rout  : f32  [2048][64]          @ 223498240     524288 B
//   consts: f32  [3048]              @ 224022528      12288 B
//   flag  : int                      @ 224034816          4 B

typedef unsigned short u16;
typedef unsigned int u32;

typedef float f32x4 __attribute__((ext_vector_type(4)));
typedef short s16x8 __attribute__((ext_vector_type(8)));
typedef __bf16 b16x8 __attribute__((ext_vector_type(8)));

template <typename V>
__device__ inline auto mfma_sel(V a, V b, f32x4 c, int)
    -> decltype(__builtin_amdgcn_mfma_f32_16x16x32_bf16(a, b, c, 0, 0, 0)) {
  return __builtin_amdgcn_mfma_f32_16x16x32_bf16(a, b, c, 0, 0, 0);
}
template <typename V>
__device__ inline f32x4 mfma_sel(V a, V b, f32x4 c, long) {
  union UU { V s; b16x8 b; };
  UU ua; ua.s = a;
  UU ub; ub.s = b;
  return __builtin_amdgcn_mfma_f32_16x16x32_bf16(ua.b, ub.b, c, 0, 0, 0);
}
__device__ inline f32x4 mfma16x16x32(s16x8 a, s16x8 b, f32x4 c) {
  return mfma_sel(a, b, c, 0);
}

__device__ inline float bf2f(u16 v) {
  union { u32 i; float f; } x; x.i = ((u32)v) << 16; return x.f;
}
__device__ inline u16 f2bf(float f) {  // round-to-nearest-even
  union { float f; u32 i; } x; x.f = f;
  u32 i = x.i;
  i += 0x7fffu + ((i >> 16) & 1u);
  return (u16)(i >> 16);
}
__device__ inline void bf2x2(u32 u, float& lo, float& hi) {
  union { u32 i; float f; } a, b;
  a.i = u << 16; b.i = u & 0xffff0000u;
  lo = a.f; hi = b.f;
}
__device__ inline float ldf(int isbf, const void* p, size_t i) {
  return isbf ? bf2f(((const u16*)p)[i]) : ((const float*)p)[i];
}
__device__ inline u16 ldb(int isbf, const void* p, size_t i) {
  return isbf ? ((const u16*)p)[i] : f2bf(((const float*)p)[i]);
}
__device__ inline float fast_tanh(float x) {
  float ax = fabsf(x);
  float e = __expf(2.0f * ax);
  float t = 1.0f - 2.0f / (e + 1.0f);
  return copysignf(t, x);
}

// ---------- fused prep: detect + consts + w1p + w2c + bbT + HT ----------
__global__ __launch_bounds__(256)
void k_prep_all(const u32* __restrict__ bwords,
                const void* b1, const void* b2, const void* bbb,
                const void* f1b, const void* f2b, const void* tab,
                const void* tbb, const void* oww, const void* obb,
                const void* hx, const void* w1, const void* w2,
                const void* bw, const void* f1w, const void* f2w,
                const void* taw, const void* tbw,
                float* __restrict__ consts, u16* __restrict__ w1p,
                u16* __restrict__ w2c, u16* __restrict__ bbT,
                u16* __restrict__ HT, int* __restrict__ flag) {
  __shared__ u16 t[64][65];
  const int tid = threadIdx.x;
  const int b = blockIdx.x;
  const u32 wd = bwords[tid & 63];
  const u32 ex = (wd >> 7) & 0xFFu;
  unsigned long long m = __ballot(ex >= 100u && ex <= 126u);
  const int isbf = (__popcll(m) >= 32) ? 1 : 0;
  if (b == 0 && tid == 0) *flag = isbf;

  if (b < 12) {
    const int e = b * 256 + tid;
    if (e >= 3048) return;
    float v;
    if (e < 32)        v = ldf(isbf, b1, e);
    else if (e < 96)   v = ldf(isbf, b2, e - 32);
    else if (e < 224)  v = ldf(isbf, bbb, e - 96);
    else if (e < 288)  v = ldf(isbf, f1b, e - 224);
    else if (e < 352)  v = ldf(isbf, f2b, e - 288);
    else if (e < 416)  v = ldf(isbf, tab, e - 352);
    else if (e < 480)  v = ldf(isbf, tbb, e - 416);
    else if (e < 992)  v = ldf(isbf, oww, e - 480);
    else if (e < 1000) v = ldf(isbf, obb, e - 992);
    else               v = ldf(isbf, hx, e - 1000);
    consts[e] = v;
  } else if (b < 20) {
    const int e = (b - 12) * 256 + tid;
    const int k = e & 63, co = e >> 6;
    w1p[e] = (k < 48) ? ldb(isbf, w1, co * 48 + k) : (u16)0;
  } else if (b < 148) {
    const int e = (b - 20) * 256 + tid;
    w2c[e] = ldb(isbf, w2, e);
  } else if (b < 662) {
    const int idx = b - 148;
    const int k0 = (idx >> 1) * 64, j0 = (idx & 1) * 64;
    #pragma unroll
    for (int i = 0; i < 16; ++i) {
      int e = tid + 256 * i;
      int kl = e >> 6, jl = e & 63;
      t[kl][jl] = ldb(isbf, bw, (size_t)(k0 + kl) * 128 + j0 + jl);
    }
    __syncthreads();
    #pragma unroll
    for (int i = 0; i < 16; ++i) {
      int e = tid + 256 * i;
      int jl = e >> 6, kl = e & 63;
      bbT[(size_t)(j0 + jl) * 16448 + k0 + kl] = t[kl][jl];
    }
  } else {
    const int idx = b - 662;
    const int h = idx >> 1, i0 = (idx & 1) * 64;
    const void* W = (h == 0) ? f1w : (h == 1) ? f2w : (h == 2) ? taw : tbw;
    #pragma unroll
    for (int i = 0; i < 16; ++i) {
      int e = tid + 256 * i;
      int il = e >> 6, cl = e & 63;
      t[il][cl] = ldb(isbf, W, (i0 + il) * 64 + cl);
    }
    __syncthreads();
    #pragma unroll
    for (int i = 0; i < 16; ++i) {
      int e = tid + 256 * i;
      int cl = e >> 6, il = e & 63;
      HT[(h * 64 + cl) * 128 + i0 + il] = t[il][cl];
    }
  }
}

// ---------- fused conv1+conv2: one image per block (R14 + strides) ----------
// LDS u32 map (conflict-free plane strides):
//   XS   @ 0     : 3 planes x (66 rows x 34 u32, stride 2256) rows 0/65 = 0
//   ZS   @ 6768  : 68 u32 zeros (conv1 K-pad plane reads)
//   A1H  @ 6836  : 16 planes (stride 624 = 34 rows x 18 u32 + 12 pad)
//   total 16820 u32 = 67280 B  -> 2 blocks/CU
__global__ __launch_bounds__(512, 2)
void k_convs(const int* __restrict__ flagp, const void* __restrict__ x,
             const u16* __restrict__ w1p, const u16* __restrict__ w2c,
             const float* __restrict__ consts, u16* __restrict__ feats) {
  __shared__ u32 lx[16820];
  const int isbf = *flagp;
  const int n = blockIdx.x;
  const int tid = threadIdx.x;
  const int wv = tid >> 6, lane = tid & 63, quad = lane >> 4, l15 = lane & 15;

  // zero: xs border rows (204) + zero strip (68) + whole a1h (9984)
  for (int e = tid; e < 10256; e += 512) {
    int idx;
    if (e < 204) {
      const int pl = e / 68;
      const int rem = e - pl * 68;
      const int r = rem / 34;
      idx = pl * 2256 + r * (65 * 34) + (rem - r * 34);
    } else if (e < 272) {
      idx = 6768 + (e - 204);
    } else {
      idx = 6836 + (e - 272);
    }
    lx[idx] = 0u;
  }
  // stage x -> XS (interior rows 1..64), shifted-pair bf16
  for (int e = tid; e < 3072; e += 512) {
    const int ci = e >> 10;
    const int rr = (e >> 4) & 63;
    const int tt = e & 15;
    u32* dst = &lx[ci * 2256 + (rr + 1) * 34];
    if (!isbf) {
      const float* src = (const float*)x + (((size_t)n * 3 + ci) * 64 + rr) * 64 + 4 * tt;
      const f32x4 v = *(const f32x4*)src;
      const float pv = tt ? src[-1] : 0.f;
      dst[2 * tt]     = (u32)f2bf(pv)   | (((u32)f2bf(v[0])) << 16);
      dst[2 * tt + 1] = (u32)f2bf(v[1]) | (((u32)f2bf(v[2])) << 16);
      if (tt == 15) { dst[32] = (u32)f2bf(v[3]); dst[33] = 0u; }
    } else {
      const u16* src = (const u16*)x + (((size_t)n * 3 + ci) * 64 + rr) * 64 + 4 * tt;
      const u16 pv = tt ? src[-1] : (u16)0;
      dst[2 * tt]     = (u32)pv | (((u32)src[0]) << 16);
      dst[2 * tt + 1] = (u32)src[1] | (((u32)src[2]) << 16);
      if (tt == 15) { dst[32] = (u32)src[3]; dst[33] = 0u; }
    }
  }
  __syncthreads();

  f32x4 acc2[8];
  #pragma unroll
  for (int rr = 0; rr < 8; ++rr) acc2[rr] = f32x4{0.f, 0.f, 0.f, 0.f};

  const int khb = (quad & 1) * 2;
  const int cih = quad >> 1;
  const int mt = wv & 3;    // conv2: co-group
  const int og = wv >> 2;   // conv2: oh-octet (oh = og*8 + rr)
  u16* lp = (u16*)lx;

  #pragma unroll
  for (int h = 0; h < 2; ++h) {
    // ---- conv1 half: co = h*16 .. h*16+15 -> A1H ----
    const s16x8 af0 = *(const s16x8*)(w1p + (h * 16 + l15) * 64 + quad * 8);
    const s16x8 af1 = *(const s16x8*)(w1p + (h * 16 + l15) * 64 + 32 + quad * 8);
    #pragma unroll
    for (int i = 0; i < 8; ++i) {
      const int nt = wv * 8 + i;
      const int oh = nt >> 1;
      const int ob = (nt & 1) * 16;
      f32x4 a1acc = f32x4{0.f, 0.f, 0.f, 0.f};
      {
        const int base = cih * 2256 + (2 * oh + khb) * 34 + ob + l15;
        union { u32 u[4]; s16x8 v; } bf;
        bf.u[0] = lx[base];
        bf.u[1] = lx[base + 1];
        bf.u[2] = lx[base + 34];
        bf.u[3] = lx[base + 35];
        a1acc = mfma16x16x32(af0, bf.v, a1acc);
      }
      {
        // ci1 = 2+cih: plane 2 real, plane 3 = K-pad -> zero strip
        const int base = (cih == 0) ? (2 * 2256 + (2 * oh + khb) * 34 + ob + l15)
                                    : (6768 + ob + l15);
        union { u32 u[4]; s16x8 v; } bf;
        bf.u[0] = lx[base];
        bf.u[1] = lx[base + 1];
        bf.u[2] = lx[base + 34];
        bf.u[3] = lx[base + 35];
        a1acc = mfma16x16x32(af1, bf.v, a1acc);
      }
      #pragma unroll
      for (int r = 0; r < 4; ++r) {
        const int co = quad * 4 + r;
        float v = a1acc[r] + consts[h * 16 + co];
        v = v > 0.f ? v : 0.f;
        lp[(6836 + co * 624 + (oh + 1) * 18) * 2 + ob + l15 + 1] = f2bf(v);
      }
    }
    __syncthreads();  // a1 half ready
    // ---- conv2 K-half: planes 16h..16h+15 ----
    // wave remap (R14): ONE w2c fragment per kst, 8 MFMA vs a1 rows.
    #pragma unroll
    for (int kst = 0; kst < 8; ++kst) {
      const int kglob = h * 8 + kst;
      const s16x8 afr =
          *(const s16x8*)(w2c + (mt * 16 + l15) * 512 + kglob * 32 + quad * 8);
      const int ci = kst * 2 + cih;
      #pragma unroll
      for (int rr = 0; rr < 8; ++rr) {
        const int row1 = 2 * (og * 8 + rr) + khb;
        const int base = 6836 + ci * 624 + row1 * 18 + l15;
        union { u32 u[4]; s16x8 v; } bf;
        bf.u[0] = lx[base];
        bf.u[1] = lx[base + 1];
        bf.u[2] = lx[base + 18];
        bf.u[3] = lx[base + 19];
        acc2[rr] = mfma16x16x32(afr, bf.v, acc2[rr]);
      }
    }
    if (h == 0) __syncthreads();  // conv2 h0 done reading before conv1 h1 writes
  }
  // ---- epilogue: feats ----
  #pragma unroll
  for (int rr = 0; rr < 8; ++rr) {
    const int oh = og * 8 + rr;
    #pragma unroll
    for (int r = 0; r < 4; ++r) {
      const int co = mt * 16 + quad * 4 + r;
      const float bias = consts[32 + co];
      float v = acc2[rr][r] + bias;
      v = v > 0.f ? v : 0.f;
      feats[(size_t)n * 16384 + co * 256 + oh * 16 + l15] = f2bf(v);
    }
  }
}

// ---------- xb partials: feats @ bb_w[:16384], split-K=16, NO atomics ------
__global__ __launch_bounds__(256)
void k_xb(const u16* __restrict__ feats, const u16* __restrict__ bbT,
          float* __restrict__ xbp) {
  const int m0 = blockIdx.x * 64;
  const int kc = blockIdx.y;
  const int kc0 = kc * 1024;
  const int tid = threadIdx.x;
  const int w = tid >> 6, lane = tid & 63, quad = lane >> 4, l15 = lane & 15;
  f32x4 acc[4][2];
  #pragma unroll
  for (int mt = 0; mt < 4; ++mt)
    #pragma unroll
    for (int i = 0; i < 2; ++i) acc[mt][i] = f32x4{0.f, 0.f, 0.f, 0.f};
  #pragma unroll 4
  for (int kst = 0; kst < 32; ++kst) {
    const int k = kc0 + kst * 32 + quad * 8;
    s16x8 afrag[4], bfrag[2];
    #pragma unroll
    for (int mt = 0; mt < 4; ++mt)
      afrag[mt] = *(const s16x8*)(feats + (size_t)(m0 + mt * 16 + l15) * 16384 + k);
    #pragma unroll
    for (int i = 0; i < 2; ++i)
      bfrag[i] = *(const s16x8*)(bbT + (size_t)((w * 2 + i) * 16 + l15) * 16448 + k);
    #pragma unroll
    for (int mt = 0; mt < 4; ++mt)
      #pragma unroll
      for (int i = 0; i < 2; ++i)
        acc[mt][i] = mfma16x16x32(afrag[mt], bfrag[i], acc[mt][i]);
  }
  float* dst = xbp + (size_t)kc * 262144;
  #pragma unroll
  for (int mt = 0; mt < 4; ++mt)
    #pragma unroll
    for (int i = 0; i < 2; ++i) {
      const int j = (w * 2 + i) * 16 + l15;
      #pragma unroll
      for (int r = 0; r < 4; ++r) {
        const int m = m0 + mt * 16 + quad * 4 + r;
        dst[m * 128 + j] = acc[mt][i][r];
      }
    }
}

// ---------- reduce split-K partials -> xb ----------
__global__ __launch_bounds__(256)
void k_xbsum(const float* __restrict__ xbp, float* __restrict__ xb) {
  const int e = blockIdx.x * 256 + threadIdx.x;
  float s = 0.f;
  #pragma unroll
  for (int kc = 0; kc < 16; ++kc) s += xbp[(size_t)kc * 262144 + e];
  xb[e] = s;
}

// ---------- CfC recurrence: one block per batch row, 3 barriers/step ----------
__global__ __launch_bounds__(256)
void k_rec(const int* __restrict__ flagp, const float* __restrict__ xb,
           const u16* __restrict__ bbT, const u16* __restrict__ HT,
           const float* __restrict__ consts, float* __restrict__ rout,
           void* __restrict__ outv) {
  __shared__ float xbl[64 * 128];
  __shared__ float h[64];
  __shared__ float bbv[128];
  __shared__ float heads[256];
  const int isbf = *flagp;
  const int b = blockIdx.x;
  const int tid = threadIdx.x;
  {
    const float* src = xb + (size_t)b * 64 * 128;
    #pragma unroll
    for (int q = 0; q < 32; ++q) xbl[q * 256 + tid] = src[q * 256 + tid];
  }
  // phase-1 weights: full K=64 column for j = tid (threads 0..127)
  float w1r[64];
  if (tid < 128) {
    const u32* src = (const u32*)(bbT + (size_t)tid * 16448 + 16384);
    #pragma unroll
    for (int q = 0; q < 32; ++q) bf2x2(src[q], w1r[2 * q], w1r[2 * q + 1]);
  }
  float w2r[128];
  {
    const u32* src = (const u32*)(HT + tid * 128);
    #pragma unroll
    for (int q = 0; q < 64; ++q) bf2x2(src[q], w2r[2 * q], w2r[2 * q + 1]);
  }
  const float hbias = consts[224 + tid];
  const float bbias = (tid < 128) ? consts[96 + tid] : 0.f;
  if (tid < 64) h[tid] = consts[1000 + b * 64 + tid];
  __syncthreads();
  for (int t = 0; t < 64; ++t) {
    if (tid < 128) {
      float p0 = 0.f, p1 = 0.f, p2 = 0.f, p3 = 0.f;
      #pragma unroll
      for (int q = 0; q < 16; ++q) {
        p0 += h[4 * q + 0] * w1r[4 * q + 0];
        p1 += h[4 * q + 1] * w1r[4 * q + 1];
        p2 += h[4 * q + 2] * w1r[4 * q + 2];
        p3 += h[4 * q + 3] * w1r[4 * q + 3];
      }
      const float s = (p0 + p1) + (p2 + p3) + xbl[t * 128 + tid] + bbias;
      bbv[tid] = 1.7159f * fast_tanh(0.666f * s);
    }
    __syncthreads();
    float c0 = 0.f, c1 = 0.f, c2 = 0.f, c3 = 0.f;
    #pragma unroll
    for (int q = 0; q < 32; ++q) {
      c0 += bbv[4 * q + 0] * w2r[4 * q + 0];
      c1 += bbv[4 * q + 1] * w2r[4 * q + 1];
      c2 += bbv[4 * q + 2] * w2r[4 * q + 2];
      c3 += bbv[4 * q + 3] * w2r[4 * q + 3];
    }
    heads[tid] = (c0 + c1) + (c2 + c3) + hbias;
    __syncthreads();
    if (tid < 64) {
      const float ff1 = fast_tanh(heads[tid]);
      const float ff2 = fast_tanh(heads[64 + tid]);
      const float ti = 1.f / (1.f + __expf(-(heads[128 + tid] + heads[192 + tid])));
      const float hn = ff1 * (1.f - ti) + ti * ff2;
      h[tid] = hn;
      rout[((size_t)b * 64 + t) * 64 + tid] = hn;
    }
    __syncthreads();
  }
  if (tid < 64) {
    if (isbf) ((u16*)outv)[16384 + b * 64 + tid] = f2bf(h[tid]);
    else      ((float*)outv)[16384 + b * 64 + tid] = h[tid];
  }
}

// ---------- logits = rout @ out_w + out_b ----------
__global__ __launch_bounds__(256)
void k_logits(const int* __restrict__ flagp, const float* __restrict__ rout,
              const float* __restrict__ consts, void* __restrict__ outv) {
  __shared__ float W[512];
  __shared__ float Bv[8];
  const int isbf = *flagp;
  const int tid = threadIdx.x;
  for (int e = tid; e < 512; e += 256) W[e] = consts[480 + e];
  if (tid < 8) Bv[tid] = consts[992 + tid];
  __syncthreads();
  const int bt = blockIdx.x * 256 + tid;
  float acc[8];
  #pragma unroll
  for (int c = 0; c < 8; ++c) acc[c] = Bv[c];
  const f32x4* r = (const f32x4*)(rout + (size_t)bt * 64);
  #pragma unroll
  for (int q = 0; q < 16; ++q) {
    f32x4 v = r[q];
    #pragma unroll
    for (int u = 0; u < 4; ++u) {
      const float rv = v[u];
      const int i = 4 * q + u;
      #pragma unroll
      for (int c = 0; c < 8; ++c) acc[c] += rv * W[i * 8 + c];
    }
  }
  if (isbf) {
    u32 pk[4];
    #pragma unroll
    for (int c = 0; c < 4; ++c)
      pk[c] = (u32)f2bf(acc[2 * c]) | ((u32)f2bf(acc[2 * c + 1]) << 16);
    *(uint4*)((u16*)outv + (size_t)bt * 8) = *(const uint4*)pk;
  } else {
    float* o = (float*)outv + (size_t)bt * 8;
    *(f32x4*)o = f32x4{acc[0], acc[1], acc[2], acc[3]};
    *(f32x4*)(o + 4) = f32x4{acc[4], acc[5], acc[6], acc[7]};
  }
}

extern "C" void kernel_launch(void* const* d_in, const int* in_sizes, int n_in,
                              void* d_out, int out_size, void* d_ws, size_t ws_size,
                              hipStream_t stream) {
  const void* x   = d_in[0];
  const void* hx  = d_in[1];
  const void* w1  = d_in[2];
  const void* b1  = d_in[3];
  const void* w2  = d_in[4];
  const void* b2  = d_in[5];
  const void* bbw = d_in[6];
  const void* bbb = d_in[7];
  const void* f1w = d_in[8];
  const void* f1b = d_in[9];
  const void* f2w = d_in[10];
  const void* f2b = d_in[11];
  const void* taw = d_in[12];
  const void* tab = d_in[13];
  const void* tbw = d_in[14];
  const void* tbb = d_in[15];
  const void* oww = d_in[16];
  const void* obb = d_in[17];

  char* ws = (char*)d_ws;
  float* xbp   = (float*)(ws);
  u16*   feats = (u16*)(ws + 150994944);
  u16*   bbT   = (u16*)(ws + 218103808);
  u16*   HT    = (u16*)(ws + 222314496);
  u16*   w1p   = (u16*)(ws + 222380032);
  u16*   w2c   = (u16*)(ws + 222384128);
  float* xb    = (float*)(ws + 222449664);
  float* rout  = (float*)(ws + 223498240);
  float* consts= (float*)(ws + 224022528);
  int*   flag  = (int*)(ws + 224034816);

  k_prep_all<<<670, 256, 0, stream>>>((const u32*)bbw, b1, b2, bbb, f1b, f2b,
                                      tab, tbb, oww, obb, hx, w1, w2, bbw,
                                      f1w, f2w, taw, tbw,
                                      consts, w1p, w2c, bbT, HT, flag);
  k_convs<<<2048, 512, 0, stream>>>(flag, x, w1p, w2c, consts, feats);
  k_xb<<<dim3(32, 16), 256, 0, stream>>>(feats, bbT, xbp);
  k_xbsum<<<1024, 256, 0, stream>>>(xbp, xb);
  k_rec<<<32, 256, 0, stream>>>(flag, xb, bbT, HT, consts, rout, d_out);
  k_logits<<<8, 256, 0, stream>>>(flag, rout, consts, d_out);
}

// Round 12
// 444.902 us; speedup vs baseline: 1.3087x; 1.0536x over previous
//
#include <hip/hip_runtime.h>
#include <stdint.h>

// DoomLiquidNet: conv(3->32,k4s2p1) -> conv(32->64,k4s2p1) -> CfC core -> logits
// Inputs f32 (detected on device; bf16 fallback kept). Compute in bf16 MFMA.
//
// R18 = exact R14 (champion: 421us total, k_convs 124us) + k_convs split into
//   4 launches of 512 blocks (nbase param) as a DIAGNOSTIC: total-k_convs has
//   been a constant ~297us across R0/R14/R17 and the top-5 table is saturated
//   by k_convs iterations, hiding the per-kernel split of the other 70%.
//   With convs dispatches at ~32us, the largest other kernel (>=59us by
//   pigeonhole) must surface with full counters. 512 blocks = exactly one
//   resident round (2 blk/CU x 256 CU) -> negligible tail cost.
// R17 post-mortem: R15 stride padding REFUTED - BANK_CONFLICT unchanged at
//   22M, and the stride constants cost VGPRs (128-pin / spill / occ 22%).
//   k_convs 124->170. Reverted. R14 stands.
// R14: conv2 wave remap (mt=wv&3, og=wv>>2): ONE w2c fragment/kst x 8 MFMA;
//   per-wave w2c traffic 64KB->16KB -> k_convs 193->124us.
//
// ws layout:
//   xbp   : f32  [16][2048][128]     @ 0           16777216 B
//   feats : bf16 [2048][16384]       @ 150994944   67108864 B
//   bbT   : bf16 [128][16448]        @ 218103808    4210688 B
//   HT    : bf16 [256][128]          @ 222314496      65536 B
//   w1p   : bf16 [32][64]            @ 222380032       4096 B
//   w2c   : bf16 [64][512]           @ 222384128      65536 B
//   xb    : f32  [2048][128]         @ 222449664    1048576 B
//   rout  : f32  [2048][64]          @ 223498240     524288 B
//   consts: f32  [3048]              @ 224022528      12288 B
//   flag  : int                      @ 224034816          4 B

typedef unsigned short u16;
typedef unsigned int u32;

typedef float f32x4 __attribute__((ext_vector_type(4)));
typedef short s16x8 __attribute__((ext_vector_type(8)));
typedef __bf16 b16x8 __attribute__((ext_vector_type(8)));

template <typename V>
__device__ inline auto mfma_sel(V a, V b, f32x4 c, int)
    -> decltype(__builtin_amdgcn_mfma_f32_16x16x32_bf16(a, b, c, 0, 0, 0)) {
  return __builtin_amdgcn_mfma_f32_16x16x32_bf16(a, b, c, 0, 0, 0);
}
template <typename V>
__device__ inline f32x4 mfma_sel(V a, V b, f32x4 c, long) {
  union UU { V s; b16x8 b; };
  UU ua; ua.s = a;
  UU ub; ub.s = b;
  return __builtin_amdgcn_mfma_f32_16x16x32_bf16(ua.b, ub.b, c, 0, 0, 0);
}
__device__ inline f32x4 mfma16x16x32(s16x8 a, s16x8 b, f32x4 c) {
  return mfma_sel(a, b, c, 0);
}

__device__ inline float bf2f(u16 v) {
  union { u32 i; float f; } x; x.i = ((u32)v) << 16; return x.f;
}
__device__ inline u16 f2bf(float f) {  // round-to-nearest-even
  union { float f; u32 i; } x; x.f = f;
  u32 i = x.i;
  i += 0x7fffu + ((i >> 16) & 1u);
  return (u16)(i >> 16);
}
__device__ inline void bf2x2(u32 u, float& lo, float& hi) {
  union { u32 i; float f; } a, b;
  a.i = u << 16; b.i = u & 0xffff0000u;
  lo = a.f; hi = b.f;
}
__device__ inline float ldf(int isbf, const void* p, size_t i) {
  return isbf ? bf2f(((const u16*)p)[i]) : ((const float*)p)[i];
}
__device__ inline u16 ldb(int isbf, const void* p, size_t i) {
  return isbf ? ((const u16*)p)[i] : f2bf(((const float*)p)[i]);
}
__device__ inline float fast_tanh(float x) {
  float ax = fabsf(x);
  float e = __expf(2.0f * ax);
  float t = 1.0f - 2.0f / (e + 1.0f);
  return copysignf(t, x);
}

// ---------- fused prep: detect + consts + w1p + w2c + bbT + HT ----------
__global__ __launch_bounds__(256)
void k_prep_all(const u32* __restrict__ bwords,
                const void* b1, const void* b2, const void* bbb,
                const void* f1b, const void* f2b, const void* tab,
                const void* tbb, const void* oww, const void* obb,
                const void* hx, const void* w1, const void* w2,
                const void* bw, const void* f1w, const void* f2w,
                const void* taw, const void* tbw,
                float* __restrict__ consts, u16* __restrict__ w1p,
                u16* __restrict__ w2c, u16* __restrict__ bbT,
                u16* __restrict__ HT, int* __restrict__ flag) {
  __shared__ u16 t[64][65];
  const int tid = threadIdx.x;
  const int b = blockIdx.x;
  const u32 wd = bwords[tid & 63];
  const u32 ex = (wd >> 7) & 0xFFu;
  unsigned long long m = __ballot(ex >= 100u && ex <= 126u);
  const int isbf = (__popcll(m) >= 32) ? 1 : 0;
  if (b == 0 && tid == 0) *flag = isbf;

  if (b < 12) {
    const int e = b * 256 + tid;
    if (e >= 3048) return;
    float v;
    if (e < 32)        v = ldf(isbf, b1, e);
    else if (e < 96)   v = ldf(isbf, b2, e - 32);
    else if (e < 224)  v = ldf(isbf, bbb, e - 96);
    else if (e < 288)  v = ldf(isbf, f1b, e - 224);
    else if (e < 352)  v = ldf(isbf, f2b, e - 288);
    else if (e < 416)  v = ldf(isbf, tab, e - 352);
    else if (e < 480)  v = ldf(isbf, tbb, e - 416);
    else if (e < 992)  v = ldf(isbf, oww, e - 480);
    else if (e < 1000) v = ldf(isbf, obb, e - 992);
    else               v = ldf(isbf, hx, e - 1000);
    consts[e] = v;
  } else if (b < 20) {
    const int e = (b - 12) * 256 + tid;
    const int k = e & 63, co = e >> 6;
    w1p[e] = (k < 48) ? ldb(isbf, w1, co * 48 + k) : (u16)0;
  } else if (b < 148) {
    const int e = (b - 20) * 256 + tid;
    w2c[e] = ldb(isbf, w2, e);
  } else if (b < 662) {
    const int idx = b - 148;
    const int k0 = (idx >> 1) * 64, j0 = (idx & 1) * 64;
    #pragma unroll
    for (int i = 0; i < 16; ++i) {
      int e = tid + 256 * i;
      int kl = e >> 6, jl = e & 63;
      t[kl][jl] = ldb(isbf, bw, (size_t)(k0 + kl) * 128 + j0 + jl);
    }
    __syncthreads();
    #pragma unroll
    for (int i = 0; i < 16; ++i) {
      int e = tid + 256 * i;
      int jl = e >> 6, kl = e & 63;
      bbT[(size_t)(j0 + jl) * 16448 + k0 + kl] = t[kl][jl];
    }
  } else {
    const int idx = b - 662;
    const int h = idx >> 1, i0 = (idx & 1) * 64;
    const void* W = (h == 0) ? f1w : (h == 1) ? f2w : (h == 2) ? taw : tbw;
    #pragma unroll
    for (int i = 0; i < 16; ++i) {
      int e = tid + 256 * i;
      int il = e >> 6, cl = e & 63;
      t[il][cl] = ldb(isbf, W, (i0 + il) * 64 + cl);
    }
    __syncthreads();
    #pragma unroll
    for (int i = 0; i < 16; ++i) {
      int e = tid + 256 * i;
      int cl = e >> 6, il = e & 63;
      HT[(h * 64 + cl) * 128 + i0 + il] = t[il][cl];
    }
  }
}

// ---------- fused conv1+conv2: one image per block (R14 structure) ----------
// LDS u32 map:
//   XS   @ 0     : 3 planes x 66 rows x 34 u32 (shifted-pair, rows 0/65 = 0)
//   ZS   @ 6732  : 68 u32 zeros (conv1 K-pad plane reads)
//   A1H  @ 6800  : 16 planes x 34 rows x 18 u32 (shifted-pair, rows 0/33 = 0)
//   total 16592 u32 = 66368 B  -> 2 blocks/CU
__global__ __launch_bounds__(512, 4)
void k_convs(const int* __restrict__ flagp, const void* __restrict__ x,
             const u16* __restrict__ w1p, const u16* __restrict__ w2c,
             const float* __restrict__ consts, u16* __restrict__ feats,
             const int nbase) {
  __shared__ u32 lx[16592];
  const int isbf = *flagp;
  const int n = nbase + blockIdx.x;
  const int tid = threadIdx.x;
  const int wv = tid >> 6, lane = tid & 63, quad = lane >> 4, l15 = lane & 15;

  // zero: xs border rows + zero strip + whole a1h (disjoint from staging)
  for (int e = tid; e < 10064; e += 512) {
    int idx;
    if (e < 204) {
      const int pl = e / 68;
      const int rem = e - pl * 68;
      const int r = rem / 34;
      idx = pl * 2244 + r * (65 * 34) + (rem - r * 34);
    } else if (e < 272) {
      idx = 6732 + (e - 204);
    } else {
      idx = 6800 + (e - 272);
    }
    lx[idx] = 0u;
  }
  // stage x -> XS (interior rows 1..64), shifted-pair bf16
  for (int e = tid; e < 3072; e += 512) {
    const int ci = e >> 10;
    const int rr = (e >> 4) & 63;
    const int tt = e & 15;
    u32* dst = &lx[(ci * 66 + rr + 1) * 34];
    if (!isbf) {
      const float* src = (const float*)x + (((size_t)n * 3 + ci) * 64 + rr) * 64 + 4 * tt;
      const f32x4 v = *(const f32x4*)src;
      const float pv = tt ? src[-1] : 0.f;
      dst[2 * tt]     = (u32)f2bf(pv)   | (((u32)f2bf(v[0])) << 16);
      dst[2 * tt + 1] = (u32)f2bf(v[1]) | (((u32)f2bf(v[2])) << 16);
      if (tt == 15) { dst[32] = (u32)f2bf(v[3]); dst[33] = 0u; }
    } else {
      const u16* src = (const u16*)x + (((size_t)n * 3 + ci) * 64 + rr) * 64 + 4 * tt;
      const u16 pv = tt ? src[-1] : (u16)0;
      dst[2 * tt]     = (u32)pv | (((u32)src[0]) << 16);
      dst[2 * tt + 1] = (u32)src[1] | (((u32)src[2]) << 16);
      if (tt == 15) { dst[32] = (u32)src[3]; dst[33] = 0u; }
    }
  }
  __syncthreads();

  f32x4 acc2[8];
  #pragma unroll
  for (int rr = 0; rr < 8; ++rr) acc2[rr] = f32x4{0.f, 0.f, 0.f, 0.f};

  const int khb = (quad & 1) * 2;
  const int cih = quad >> 1;
  const int mt = wv & 3;    // conv2: co-group
  const int og = wv >> 2;   // conv2: oh-octet (oh = og*8 + rr)
  u16* lp = (u16*)lx;

  #pragma unroll
  for (int h = 0; h < 2; ++h) {
    // ---- conv1 half: co = h*16 .. h*16+15 -> A1H ----
    const s16x8 af0 = *(const s16x8*)(w1p + (h * 16 + l15) * 64 + quad * 8);
    const s16x8 af1 = *(const s16x8*)(w1p + (h * 16 + l15) * 64 + 32 + quad * 8);
    #pragma unroll
    for (int i = 0; i < 8; ++i) {
      const int nt = wv * 8 + i;
      const int oh = nt >> 1;
      const int ob = (nt & 1) * 16;
      f32x4 a1acc = f32x4{0.f, 0.f, 0.f, 0.f};
      {
        const int base = (cih * 66 + 2 * oh + khb) * 34 + ob + l15;
        union { u32 u[4]; s16x8 v; } bf;
        bf.u[0] = lx[base];
        bf.u[1] = lx[base + 1];
        bf.u[2] = lx[base + 34];
        bf.u[3] = lx[base + 35];
        a1acc = mfma16x16x32(af0, bf.v, a1acc);
      }
      {
        const int ci1 = 2 + cih;  // 2 or 3 (3 = K-pad -> zero strip)
        const int base = (ci1 < 3) ? ((ci1 * 66 + 2 * oh + khb) * 34 + ob + l15)
                                   : (6732 + ob + l15);
        union { u32 u[4]; s16x8 v; } bf;
        bf.u[0] = lx[base];
        bf.u[1] = lx[base + 1];
        bf.u[2] = lx[base + 34];
        bf.u[3] = lx[base + 35];
        a1acc = mfma16x16x32(af1, bf.v, a1acc);
      }
      #pragma unroll
      for (int r = 0; r < 4; ++r) {
        const int co = quad * 4 + r;
        float v = a1acc[r] + consts[h * 16 + co];
        v = v > 0.f ? v : 0.f;
        lp[(6800 + (co * 34 + oh + 1) * 18) * 2 + ob + l15 + 1] = f2bf(v);
      }
    }
    __syncthreads();  // a1 half ready
    // ---- conv2 K-half: planes 16h..16h+15 ----
    // wave remap: ONE w2c fragment per kst (mt fixed), 8 MFMA vs a1 rows.
    #pragma unroll
    for (int kst = 0; kst < 8; ++kst) {
      const int kglob = h * 8 + kst;
      const s16x8 afr =
          *(const s16x8*)(w2c + (mt * 16 + l15) * 512 + kglob * 32 + quad * 8);
      const int ci = kst * 2 + cih;
      #pragma unroll
      for (int rr = 0; rr < 8; ++rr) {
        const int row1 = 2 * (og * 8 + rr) + khb;
        const int base = 6800 + (ci * 34 + row1) * 18 + l15;
        union { u32 u[4]; s16x8 v; } bf;
        bf.u[0] = lx[base];
        bf.u[1] = lx[base + 1];
        bf.u[2] = lx[base + 18];
        bf.u[3] = lx[base + 19];
        acc2[rr] = mfma16x16x32(afr, bf.v, acc2[rr]);
      }
    }
    if (h == 0) __syncthreads();  // conv2 h0 done reading before conv1 h1 writes
  }
  // ---- epilogue: feats ----
  #pragma unroll
  for (int rr = 0; rr < 8; ++rr) {
    const int oh = og * 8 + rr;
    #pragma unroll
    for (int r = 0; r < 4; ++r) {
      const int co = mt * 16 + quad * 4 + r;
      const float bias = consts[32 + co];
      float v = acc2[rr][r] + bias;
      v = v > 0.f ? v : 0.f;
      feats[(size_t)n * 16384 + co * 256 + oh * 16 + l15] = f2bf(v);
    }
  }
}

// ---------- xb partials: feats @ bb_w[:16384], split-K=16, NO atomics ------
__global__ __launch_bounds__(256)
void k_xb(const u16* __restrict__ feats, const u16* __restrict__ bbT,
          float* __restrict__ xbp) {
  const int m0 = blockIdx.x * 64;
  const int kc = blockIdx.y;
  const int kc0 = kc * 1024;
  const int tid = threadIdx.x;
  const int w = tid >> 6, lane = tid & 63, quad = lane >> 4, l15 = lane & 15;
  f32x4 acc[4][2];
  #pragma unroll
  for (int mt = 0; mt < 4; ++mt)
    #pragma unroll
    for (int i = 0; i < 2; ++i) acc[mt][i] = f32x4{0.f, 0.f, 0.f, 0.f};
  #pragma unroll 4
  for (int kst = 0; kst < 32; ++kst) {
    const int k = kc0 + kst * 32 + quad * 8;
    s16x8 afrag[4], bfrag[2];
    #pragma unroll
    for (int mt = 0; mt < 4; ++mt)
      afrag[mt] = *(const s16x8*)(feats + (size_t)(m0 + mt * 16 + l15) * 16384 + k);
    #pragma unroll
    for (int i = 0; i < 2; ++i)
      bfrag[i] = *(const s16x8*)(bbT + (size_t)((w * 2 + i) * 16 + l15) * 16448 + k);
    #pragma unroll
    for (int mt = 0; mt < 4; ++mt)
      #pragma unroll
      for (int i = 0; i < 2; ++i)
        acc[mt][i] = mfma16x16x32(afrag[mt], bfrag[i], acc[mt][i]);
  }
  float* dst = xbp + (size_t)kc * 262144;
  #pragma unroll
  for (int mt = 0; mt < 4; ++mt)
    #pragma unroll
    for (int i = 0; i < 2; ++i) {
      const int j = (w * 2 + i) * 16 + l15;
      #pragma unroll
      for (int r = 0; r < 4; ++r) {
        const int m = m0 + mt * 16 + quad * 4 + r;
        dst[m * 128 + j] = acc[mt][i][r];
      }
    }
}

// ---------- reduce split-K partials -> xb ----------
__global__ __launch_bounds__(256)
void k_xbsum(const float* __restrict__ xbp, float* __restrict__ xb) {
  const int e = blockIdx.x * 256 + threadIdx.x;
  float s = 0.f;
  #pragma unroll
  for (int kc = 0; kc < 16; ++kc) s += xbp[(size_t)kc * 262144 + e];
  xb[e] = s;
}

// ---------- CfC recurrence: one block per batch row, 3 barriers/step ----------
__global__ __launch_bounds__(256)
void k_rec(const int* __restrict__ flagp, const float* __restrict__ xb,
           const u16* __restrict__ bbT, const u16* __restrict__ HT,
           const float* __restrict__ consts, float* __restrict__ rout,
           void* __restrict__ outv) {
  __shared__ float xbl[64 * 128];
  __shared__ float h[64];
  __shared__ float bbv[128];
  __shared__ float heads[256];
  const int isbf = *flagp;
  const int b = blockIdx.x;
  const int tid = threadIdx.x;
  {
    const float* src = xb + (size_t)b * 64 * 128;
    #pragma unroll
    for (int q = 0; q < 32; ++q) xbl[q * 256 + tid] = src[q * 256 + tid];
  }
  // phase-1 weights: full K=64 column for j = tid (threads 0..127)
  float w1r[64];
  if (tid < 128) {
    const u32* src = (const u32*)(bbT + (size_t)tid * 16448 + 16384);
    #pragma unroll
    for (int q = 0; q < 32; ++q) bf2x2(src[q], w1r[2 * q], w1r[2 * q + 1]);
  }
  float w2r[128];
  {
    const u32* src = (const u32*)(HT + tid * 128);
    #pragma unroll
    for (int q = 0; q < 64; ++q) bf2x2(src[q], w2r[2 * q], w2r[2 * q + 1]);
  }
  const float hbias = consts[224 + tid];
  const float bbias = (tid < 128) ? consts[96 + tid] : 0.f;
  if (tid < 64) h[tid] = consts[1000 + b * 64 + tid];
  __syncthreads();
  for (int t = 0; t < 64; ++t) {
    if (tid < 128) {
      float p0 = 0.f, p1 = 0.f, p2 = 0.f, p3 = 0.f;
      #pragma unroll
      for (int q = 0; q < 16; ++q) {
        p0 += h[4 * q + 0] * w1r[4 * q + 0];
        p1 += h[4 * q + 1] * w1r[4 * q + 1];
        p2 += h[4 * q + 2] * w1r[4 * q + 2];
        p3 += h[4 * q + 3] * w1r[4 * q + 3];
      }
      const float s = (p0 + p1) + (p2 + p3) + xbl[t * 128 + tid] + bbias;
      bbv[tid] = 1.7159f * fast_tanh(0.666f * s);
    }
    __syncthreads();
    float c0 = 0.f, c1 = 0.f, c2 = 0.f, c3 = 0.f;
    #pragma unroll
    for (int q = 0; q < 32; ++q) {
      c0 += bbv[4 * q + 0] * w2r[4 * q + 0];
      c1 += bbv[4 * q + 1] * w2r[4 * q + 1];
      c2 += bbv[4 * q + 2] * w2r[4 * q + 2];
      c3 += bbv[4 * q + 3] * w2r[4 * q + 3];
    }
    heads[tid] = (c0 + c1) + (c2 + c3) + hbias;
    __syncthreads();
    if (tid < 64) {
      const float ff1 = fast_tanh(heads[tid]);
      const float ff2 = fast_tanh(heads[64 + tid]);
      const float ti = 1.f / (1.f + __expf(-(heads[128 + tid] + heads[192 + tid])));
      const float hn = ff1 * (1.f - ti) + ti * ff2;
      h[tid] = hn;
      rout[((size_t)b * 64 + t) * 64 + tid] = hn;
    }
    __syncthreads();
  }
  if (tid < 64) {
    if (isbf) ((u16*)outv)[16384 + b * 64 + tid] = f2bf(h[tid]);
    else      ((float*)outv)[16384 + b * 64 + tid] = h[tid];
  }
}

// ---------- logits = rout @ out_w + out_b ----------
__global__ __launch_bounds__(256)
void k_logits(const int* __restrict__ flagp, const float* __restrict__ rout,
              const float* __restrict__ consts, void* __restrict__ outv) {
  __shared__ float W[512];
  __shared__ float Bv[8];
  const int isbf = *flagp;
  const int tid = threadIdx.x;
  for (int e = tid; e < 512; e += 256) W[e] = consts[480 + e];
  if (tid < 8) Bv[tid] = consts[992 + tid];
  __syncthreads();
  const int bt = blockIdx.x * 256 + tid;
  float acc[8];
  #pragma unroll
  for (int c = 0; c < 8; ++c) acc[c] = Bv[c];
  const f32x4* r = (const f32x4*)(rout + (size_t)bt * 64);
  #pragma unroll
  for (int q = 0; q < 16; ++q) {
    f32x4 v = r[q];
    #pragma unroll
    for (int u = 0; u < 4; ++u) {
      const float rv = v[u];
      const int i = 4 * q + u;
      #pragma unroll
      for (int c = 0; c < 8; ++c) acc[c] += rv * W[i * 8 + c];
    }
  }
  if (isbf) {
    u32 pk[4];
    #pragma unroll
    for (int c = 0; c < 4; ++c)
      pk[c] = (u32)f2bf(acc[2 * c]) | ((u32)f2bf(acc[2 * c + 1]) << 16);
    *(uint4*)((u16*)outv + (size_t)bt * 8) = *(const uint4*)pk;
  } else {
    float* o = (float*)outv + (size_t)bt * 8;
    *(f32x4*)o = f32x4{acc[0], acc[1], acc[2], acc[3]};
    *(f32x4*)(o + 4) = f32x4{acc[4], acc[5], acc[6], acc[7]};
  }
}

extern "C" void kernel_launch(void* const* d_in, const int* in_sizes, int n_in,
                              void* d_out, int out_size, void* d_ws, size_t ws_size,
                              hipStream_t stream) {
  const void* x   = d_in[0];
  const void* hx  = d_in[1];
  const void* w1  = d_in[2];
  const void* b1  = d_in[3];
  const void* w2  = d_in[4];
  const void* b2  = d_in[5];
  const void* bbw = d_in[6];
  const void* bbb = d_in[7];
  const void* f1w = d_in[8];
  const void* f1b = d_in[9];
  const void* f2w = d_in[10];
  const void* f2b = d_in[11];
  const void* taw = d_in[12];
  const void* tab = d_in[13];
  const void* tbw = d_in[14];
  const void* tbb = d_in[15];
  const void* oww = d_in[16];
  const void* obb = d_in[17];

  char* ws = (char*)d_ws;
  float* xbp   = (float*)(ws);
  u16*   feats = (u16*)(ws + 150994944);
  u16*   bbT   = (u16*)(ws + 218103808);
  u16*   HT    = (u16*)(ws + 222314496);
  u16*   w1p   = (u16*)(ws + 222380032);
  u16*   w2c   = (u16*)(ws + 222384128);
  float* xb    = (float*)(ws + 222449664);
  float* rout  = (float*)(ws + 223498240);
  float* consts= (float*)(ws + 224022528);
  int*   flag  = (int*)(ws + 224034816);

  k_prep_all<<<670, 256, 0, stream>>>((const u32*)bbw, b1, b2, bbb, f1b, f2b,
                                      tab, tbb, oww, obb, hx, w1, w2, bbw,
                                      f1w, f2w, taw, tbw,
                                      consts, w1p, w2c, bbT, HT, flag);
  k_convs<<<512, 512, 0, stream>>>(flag, x, w1p, w2c, consts, feats, 0);
  k_convs<<<512, 512, 0, stream>>>(flag, x, w1p, w2c, consts, feats, 512);
  k_convs<<<512, 512, 0, stream>>>(flag, x, w1p, w2c, consts, feats, 1024);
  k_convs<<<512, 512, 0, stream>>>(flag, x, w1p, w2c, consts, feats, 1536);
  k_xb<<<dim3(32, 16), 256, 0, stream>>>(feats, bbT, xbp);
  k_xbsum<<<1024, 256, 0, stream>>>(xbp, xb);
  k_rec<<<32, 256, 0, stream>>>(flag, xb, bbT, HT, consts, rout, d_out);
  k_logits<<<8, 256, 0, stream>>>(flag, rout, consts, d_out);
}

// Round 13
// 422.621 us; speedup vs baseline: 1.3777x; 1.0527x over previous
//
#include <hip/hip_runtime.h>
#include <stdint.h>

// DoomLiquidNet: conv(3->32,k4s2p1) -> conv(32->64,k4s2p1) -> CfC core -> logits
// Inputs f32 (detected on device; bf16 fallback kept). Compute in bf16 MFMA.
//
// R19 = R14 k_convs (champion, 124us) + k_rec __launch_bounds__(256,1).
//   R18 diagnostic surfaced k_rec at 102.9us with VGPR_Count=132 while the
//   kernel caches w1r[64]+w2r[128]=192 weight floats in registers -> ~90
//   regs/thread spilled to scratch, re-loaded EVERY one of 64 serial steps
//   (occ 1.4%, VALU 2.7%, HBM 0.2% -> pure scratch-latency on the critical
//   path). (256,1) raises the cap to 256 >= demand -> no spill. Occupancy
//   is irrelevant here (32 blocks on 32 CUs, latency-bound serial loop).
// R14: conv2 wave remap (mt=wv&3, og=wv>>2): ONE w2c fragment/kst x 8 MFMA;
//   per-wave w2c traffic 64KB->16KB -> k_convs 193->124us.
// R17 lesson: stride-padding refuted (conflicts unchanged, cost VGPRs).
//
// ws layout:
//   xbp   : f32  [16][2048][128]     @ 0           16777216 B
//   feats : bf16 [2048][16384]       @ 150994944   67108864 B
//   bbT   : bf16 [128][16448]        @ 218103808    4210688 B
//   HT    : bf16 [256][128]          @ 222314496      65536 B
//   w1p   : bf16 [32][64]            @ 222380032       4096 B
//   w2c   : bf16 [64][512]           @ 222384128      65536 B
//   xb    : f32  [2048][128]         @ 222449664    1048576 B
//   rout  : f32  [2048][64]          @ 223498240     524288 B
//   consts: f32  [3048]              @ 224022528      12288 B
//   flag  : int                      @ 224034816          4 B

typedef unsigned short u16;
typedef unsigned int u32;

typedef float f32x4 __attribute__((ext_vector_type(4)));
typedef short s16x8 __attribute__((ext_vector_type(8)));
typedef __bf16 b16x8 __attribute__((ext_vector_type(8)));

template <typename V>
__device__ inline auto mfma_sel(V a, V b, f32x4 c, int)
    -> decltype(__builtin_amdgcn_mfma_f32_16x16x32_bf16(a, b, c, 0, 0, 0)) {
  return __builtin_amdgcn_mfma_f32_16x16x32_bf16(a, b, c, 0, 0, 0);
}
template <typename V>
__device__ inline f32x4 mfma_sel(V a, V b, f32x4 c, long) {
  union UU { V s; b16x8 b; };
  UU ua; ua.s = a;
  UU ub; ub.s = b;
  return __builtin_amdgcn_mfma_f32_16x16x32_bf16(ua.b, ub.b, c, 0, 0, 0);
}
__device__ inline f32x4 mfma16x16x32(s16x8 a, s16x8 b, f32x4 c) {
  return mfma_sel(a, b, c, 0);
}

__device__ inline float bf2f(u16 v) {
  union { u32 i; float f; } x; x.i = ((u32)v) << 16; return x.f;
}
__device__ inline u16 f2bf(float f) {  // round-to-nearest-even
  union { float f; u32 i; } x; x.f = f;
  u32 i = x.i;
  i += 0x7fffu + ((i >> 16) & 1u);
  return (u16)(i >> 16);
}
__device__ inline void bf2x2(u32 u, float& lo, float& hi) {
  union { u32 i; float f; } a, b;
  a.i = u << 16; b.i = u & 0xffff0000u;
  lo = a.f; hi = b.f;
}
__device__ inline float ldf(int isbf, const void* p, size_t i) {
  return isbf ? bf2f(((const u16*)p)[i]) : ((const float*)p)[i];
}
__device__ inline u16 ldb(int isbf, const void* p, size_t i) {
  return isbf ? ((const u16*)p)[i] : f2bf(((const float*)p)[i]);
}
__device__ inline float fast_tanh(float x) {
  float ax = fabsf(x);
  float e = __expf(2.0f * ax);
  float t = 1.0f - 2.0f / (e + 1.0f);
  return copysignf(t, x);
}

// ---------- fused prep: detect + consts + w1p + w2c + bbT + HT ----------
__global__ __launch_bounds__(256)
void k_prep_all(const u32* __restrict__ bwords,
                const void* b1, const void* b2, const void* bbb,
                const void* f1b, const void* f2b, const void* tab,
                const void* tbb, const void* oww, const void* obb,
                const void* hx, const void* w1, const void* w2,
                const void* bw, const void* f1w, const void* f2w,
                const void* taw, const void* tbw,
                float* __restrict__ consts, u16* __restrict__ w1p,
                u16* __restrict__ w2c, u16* __restrict__ bbT,
                u16* __restrict__ HT, int* __restrict__ flag) {
  __shared__ u16 t[64][65];
  const int tid = threadIdx.x;
  const int b = blockIdx.x;
  const u32 wd = bwords[tid & 63];
  const u32 ex = (wd >> 7) & 0xFFu;
  unsigned long long m = __ballot(ex >= 100u && ex <= 126u);
  const int isbf = (__popcll(m) >= 32) ? 1 : 0;
  if (b == 0 && tid == 0) *flag = isbf;

  if (b < 12) {
    const int e = b * 256 + tid;
    if (e >= 3048) return;
    float v;
    if (e < 32)        v = ldf(isbf, b1, e);
    else if (e < 96)   v = ldf(isbf, b2, e - 32);
    else if (e < 224)  v = ldf(isbf, bbb, e - 96);
    else if (e < 288)  v = ldf(isbf, f1b, e - 224);
    else if (e < 352)  v = ldf(isbf, f2b, e - 288);
    else if (e < 416)  v = ldf(isbf, tab, e - 352);
    else if (e < 480)  v = ldf(isbf, tbb, e - 416);
    else if (e < 992)  v = ldf(isbf, oww, e - 480);
    else if (e < 1000) v = ldf(isbf, obb, e - 992);
    else               v = ldf(isbf, hx, e - 1000);
    consts[e] = v;
  } else if (b < 20) {
    const int e = (b - 12) * 256 + tid;
    const int k = e & 63, co = e >> 6;
    w1p[e] = (k < 48) ? ldb(isbf, w1, co * 48 + k) : (u16)0;
  } else if (b < 148) {
    const int e = (b - 20) * 256 + tid;
    w2c[e] = ldb(isbf, w2, e);
  } else if (b < 662) {
    const int idx = b - 148;
    const int k0 = (idx >> 1) * 64, j0 = (idx & 1) * 64;
    #pragma unroll
    for (int i = 0; i < 16; ++i) {
      int e = tid + 256 * i;
      int kl = e >> 6, jl = e & 63;
      t[kl][jl] = ldb(isbf, bw, (size_t)(k0 + kl) * 128 + j0 + jl);
    }
    __syncthreads();
    #pragma unroll
    for (int i = 0; i < 16; ++i) {
      int e = tid + 256 * i;
      int jl = e >> 6, kl = e & 63;
      bbT[(size_t)(j0 + jl) * 16448 + k0 + kl] = t[kl][jl];
    }
  } else {
    const int idx = b - 662;
    const int h = idx >> 1, i0 = (idx & 1) * 64;
    const void* W = (h == 0) ? f1w : (h == 1) ? f2w : (h == 2) ? taw : tbw;
    #pragma unroll
    for (int i = 0; i < 16; ++i) {
      int e = tid + 256 * i;
      int il = e >> 6, cl = e & 63;
      t[il][cl] = ldb(isbf, W, (i0 + il) * 64 + cl);
    }
    __syncthreads();
    #pragma unroll
    for (int i = 0; i < 16; ++i) {
      int e = tid + 256 * i;
      int cl = e >> 6, il = e & 63;
      HT[(h * 64 + cl) * 128 + i0 + il] = t[il][cl];
    }
  }
}

// ---------- fused conv1+conv2: one image per block (R14 structure) ----------
// LDS u32 map:
//   XS   @ 0     : 3 planes x 66 rows x 34 u32 (shifted-pair, rows 0/65 = 0)
//   ZS   @ 6732  : 68 u32 zeros (conv1 K-pad plane reads)
//   A1H  @ 6800  : 16 planes x 34 rows x 18 u32 (shifted-pair, rows 0/33 = 0)
//   total 16592 u32 = 66368 B  -> 2 blocks/CU
__global__ __launch_bounds__(512, 4)
void k_convs(const int* __restrict__ flagp, const void* __restrict__ x,
             const u16* __restrict__ w1p, const u16* __restrict__ w2c,
             const float* __restrict__ consts, u16* __restrict__ feats) {
  __shared__ u32 lx[16592];
  const int isbf = *flagp;
  const int n = blockIdx.x;
  const int tid = threadIdx.x;
  const int wv = tid >> 6, lane = tid & 63, quad = lane >> 4, l15 = lane & 15;

  // zero: xs border rows + zero strip + whole a1h (disjoint from staging)
  for (int e = tid; e < 10064; e += 512) {
    int idx;
    if (e < 204) {
      const int pl = e / 68;
      const int rem = e - pl * 68;
      const int r = rem / 34;
      idx = pl * 2244 + r * (65 * 34) + (rem - r * 34);
    } else if (e < 272) {
      idx = 6732 + (e - 204);
    } else {
      idx = 6800 + (e - 272);
    }
    lx[idx] = 0u;
  }
  // stage x -> XS (interior rows 1..64), shifted-pair bf16
  for (int e = tid; e < 3072; e += 512) {
    const int ci = e >> 10;
    const int rr = (e >> 4) & 63;
    const int tt = e & 15;
    u32* dst = &lx[(ci * 66 + rr + 1) * 34];
    if (!isbf) {
      const float* src = (const float*)x + (((size_t)n * 3 + ci) * 64 + rr) * 64 + 4 * tt;
      const f32x4 v = *(const f32x4*)src;
      const float pv = tt ? src[-1] : 0.f;
      dst[2 * tt]     = (u32)f2bf(pv)   | (((u32)f2bf(v[0])) << 16);
      dst[2 * tt + 1] = (u32)f2bf(v[1]) | (((u32)f2bf(v[2])) << 16);
      if (tt == 15) { dst[32] = (u32)f2bf(v[3]); dst[33] = 0u; }
    } else {
      const u16* src = (const u16*)x + (((size_t)n * 3 + ci) * 64 + rr) * 64 + 4 * tt;
      const u16 pv = tt ? src[-1] : (u16)0;
      dst[2 * tt]     = (u32)pv | (((u32)src[0]) << 16);
      dst[2 * tt + 1] = (u32)src[1] | (((u32)src[2]) << 16);
      if (tt == 15) { dst[32] = (u32)src[3]; dst[33] = 0u; }
    }
  }
  __syncthreads();

  f32x4 acc2[8];
  #pragma unroll
  for (int rr = 0; rr < 8; ++rr) acc2[rr] = f32x4{0.f, 0.f, 0.f, 0.f};

  const int khb = (quad & 1) * 2;
  const int cih = quad >> 1;
  const int mt = wv & 3;    // conv2: co-group
  const int og = wv >> 2;   // conv2: oh-octet (oh = og*8 + rr)
  u16* lp = (u16*)lx;

  #pragma unroll
  for (int h = 0; h < 2; ++h) {
    // ---- conv1 half: co = h*16 .. h*16+15 -> A1H ----
    const s16x8 af0 = *(const s16x8*)(w1p + (h * 16 + l15) * 64 + quad * 8);
    const s16x8 af1 = *(const s16x8*)(w1p + (h * 16 + l15) * 64 + 32 + quad * 8);
    #pragma unroll
    for (int i = 0; i < 8; ++i) {
      const int nt = wv * 8 + i;
      const int oh = nt >> 1;
      const int ob = (nt & 1) * 16;
      f32x4 a1acc = f32x4{0.f, 0.f, 0.f, 0.f};
      {
        const int base = (cih * 66 + 2 * oh + khb) * 34 + ob + l15;
        union { u32 u[4]; s16x8 v; } bf;
        bf.u[0] = lx[base];
        bf.u[1] = lx[base + 1];
        bf.u[2] = lx[base + 34];
        bf.u[3] = lx[base + 35];
        a1acc = mfma16x16x32(af0, bf.v, a1acc);
      }
      {
        const int ci1 = 2 + cih;  // 2 or 3 (3 = K-pad -> zero strip)
        const int base = (ci1 < 3) ? ((ci1 * 66 + 2 * oh + khb) * 34 + ob + l15)
                                   : (6732 + ob + l15);
        union { u32 u[4]; s16x8 v; } bf;
        bf.u[0] = lx[base];
        bf.u[1] = lx[base + 1];
        bf.u[2] = lx[base + 34];
        bf.u[3] = lx[base + 35];
        a1acc = mfma16x16x32(af1, bf.v, a1acc);
      }
      #pragma unroll
      for (int r = 0; r < 4; ++r) {
        const int co = quad * 4 + r;
        float v = a1acc[r] + consts[h * 16 + co];
        v = v > 0.f ? v : 0.f;
        lp[(6800 + (co * 34 + oh + 1) * 18) * 2 + ob + l15 + 1] = f2bf(v);
      }
    }
    __syncthreads();  // a1 half ready
    // ---- conv2 K-half: planes 16h..16h+15 ----
    // wave remap: ONE w2c fragment per kst (mt fixed), 8 MFMA vs a1 rows.
    #pragma unroll
    for (int kst = 0; kst < 8; ++kst) {
      const int kglob = h * 8 + kst;
      const s16x8 afr =
          *(const s16x8*)(w2c + (mt * 16 + l15) * 512 + kglob * 32 + quad * 8);
      const int ci = kst * 2 + cih;
      #pragma unroll
      for (int rr = 0; rr < 8; ++rr) {
        const int row1 = 2 * (og * 8 + rr) + khb;
        const int base = 6800 + (ci * 34 + row1) * 18 + l15;
        union { u32 u[4]; s16x8 v; } bf;
        bf.u[0] = lx[base];
        bf.u[1] = lx[base + 1];
        bf.u[2] = lx[base + 18];
        bf.u[3] = lx[base + 19];
        acc2[rr] = mfma16x16x32(afr, bf.v, acc2[rr]);
      }
    }
    if (h == 0) __syncthreads();  // conv2 h0 done reading before conv1 h1 writes
  }
  // ---- epilogue: feats ----
  #pragma unroll
  for (int rr = 0; rr < 8; ++rr) {
    const int oh = og * 8 + rr;
    #pragma unroll
    for (int r = 0; r < 4; ++r) {
      const int co = mt * 16 + quad * 4 + r;
      const float bias = consts[32 + co];
      float v = acc2[rr][r] + bias;
      v = v > 0.f ? v : 0.f;
      feats[(size_t)n * 16384 + co * 256 + oh * 16 + l15] = f2bf(v);
    }
  }
}

// ---------- xb partials: feats @ bb_w[:16384], split-K=16, NO atomics ------
__global__ __launch_bounds__(256)
void k_xb(const u16* __restrict__ feats, const u16* __restrict__ bbT,
          float* __restrict__ xbp) {
  const int m0 = blockIdx.x * 64;
  const int kc = blockIdx.y;
  const int kc0 = kc * 1024;
  const int tid = threadIdx.x;
  const int w = tid >> 6, lane = tid & 63, quad = lane >> 4, l15 = lane & 15;
  f32x4 acc[4][2];
  #pragma unroll
  for (int mt = 0; mt < 4; ++mt)
    #pragma unroll
    for (int i = 0; i < 2; ++i) acc[mt][i] = f32x4{0.f, 0.f, 0.f, 0.f};
  #pragma unroll 4
  for (int kst = 0; kst < 32; ++kst) {
    const int k = kc0 + kst * 32 + quad * 8;
    s16x8 afrag[4], bfrag[2];
    #pragma unroll
    for (int mt = 0; mt < 4; ++mt)
      afrag[mt] = *(const s16x8*)(feats + (size_t)(m0 + mt * 16 + l15) * 16384 + k);
    #pragma unroll
    for (int i = 0; i < 2; ++i)
      bfrag[i] = *(const s16x8*)(bbT + (size_t)((w * 2 + i) * 16 + l15) * 16448 + k);
    #pragma unroll
    for (int mt = 0; mt < 4; ++mt)
      #pragma unroll
      for (int i = 0; i < 2; ++i)
        acc[mt][i] = mfma16x16x32(afrag[mt], bfrag[i], acc[mt][i]);
  }
  float* dst = xbp + (size_t)kc * 262144;
  #pragma unroll
  for (int mt = 0; mt < 4; ++mt)
    #pragma unroll
    for (int i = 0; i < 2; ++i) {
      const int j = (w * 2 + i) * 16 + l15;
      #pragma unroll
      for (int r = 0; r < 4; ++r) {
        const int m = m0 + mt * 16 + quad * 4 + r;
        dst[m * 128 + j] = acc[mt][i][r];
      }
    }
}

// ---------- reduce split-K partials -> xb ----------
__global__ __launch_bounds__(256)
void k_xbsum(const float* __restrict__ xbp, float* __restrict__ xb) {
  const int e = blockIdx.x * 256 + threadIdx.x;
  float s = 0.f;
  #pragma unroll
  for (int kc = 0; kc < 16; ++kc) s += xbp[(size_t)kc * 262144 + e];
  xb[e] = s;
}

// ---------- CfC recurrence: one block per batch row, 3 barriers/step --------
// R19: __launch_bounds__(256, 1) -> VGPR cap 256 >= demand (~222: w1r[64] +
//   w2r[128] + temps). R18 measured VGPR_Count=132 + scratch spill re-loaded
//   every serial step -> 103us at 2.7% VALU. Occupancy is irrelevant here
//   (32 blocks on 32 CUs); registers ARE the resource that matters.
__global__ __launch_bounds__(256, 1)
void k_rec(const int* __restrict__ flagp, const float* __restrict__ xb,
           const u16* __restrict__ bbT, const u16* __restrict__ HT,
           const float* __restrict__ consts, float* __restrict__ rout,
           void* __restrict__ outv) {
  __shared__ float xbl[64 * 128];
  __shared__ float h[64];
  __shared__ float bbv[128];
  __shared__ float heads[256];
  const int isbf = *flagp;
  const int b = blockIdx.x;
  const int tid = threadIdx.x;
  {
    const float* src = xb + (size_t)b * 64 * 128;
    #pragma unroll
    for (int q = 0; q < 32; ++q) xbl[q * 256 + tid] = src[q * 256 + tid];
  }
  // phase-1 weights: full K=64 column for j = tid (threads 0..127)
  float w1r[64];
  if (tid < 128) {
    const u32* src = (const u32*)(bbT + (size_t)tid * 16448 + 16384);
    #pragma unroll
    for (int q = 0; q < 32; ++q) bf2x2(src[q], w1r[2 * q], w1r[2 * q + 1]);
  }
  float w2r[128];
  {
    const u32* src = (const u32*)(HT + tid * 128);
    #pragma unroll
    for (int q = 0; q < 64; ++q) bf2x2(src[q], w2r[2 * q], w2r[2 * q + 1]);
  }
  const float hbias = consts[224 + tid];
  const float bbias = (tid < 128) ? consts[96 + tid] : 0.f;
  if (tid < 64) h[tid] = consts[1000 + b * 64 + tid];
  __syncthreads();
  for (int t = 0; t < 64; ++t) {
    if (tid < 128) {
      float p0 = 0.f, p1 = 0.f, p2 = 0.f, p3 = 0.f;
      #pragma unroll
      for (int q = 0; q < 16; ++q) {
        p0 += h[4 * q + 0] * w1r[4 * q + 0];
        p1 += h[4 * q + 1] * w1r[4 * q + 1];
        p2 += h[4 * q + 2] * w1r[4 * q + 2];
        p3 += h[4 * q + 3] * w1r[4 * q + 3];
      }
      const float s = (p0 + p1) + (p2 + p3) + xbl[t * 128 + tid] + bbias;
      bbv[tid] = 1.7159f * fast_tanh(0.666f * s);
    }
    __syncthreads();
    float c0 = 0.f, c1 = 0.f, c2 = 0.f, c3 = 0.f;
    #pragma unroll
    for (int q = 0; q < 32; ++q) {
      c0 += bbv[4 * q + 0] * w2r[4 * q + 0];
      c1 += bbv[4 * q + 1] * w2r[4 * q + 1];
      c2 += bbv[4 * q + 2] * w2r[4 * q + 2];
      c3 += bbv[4 * q + 3] * w2r[4 * q + 3];
    }
    heads[tid] = (c0 + c1) + (c2 + c3) + hbias;
    __syncthreads();
    if (tid < 64) {
      const float ff1 = fast_tanh(heads[tid]);
      const float ff2 = fast_tanh(heads[64 + tid]);
      const float ti = 1.f / (1.f + __expf(-(heads[128 + tid] + heads[192 + tid])));
      const float hn = ff1 * (1.f - ti) + ti * ff2;
      h[tid] = hn;
      rout[((size_t)b * 64 + t) * 64 + tid] = hn;
    }
    __syncthreads();
  }
  if (tid < 64) {
    if (isbf) ((u16*)outv)[16384 + b * 64 + tid] = f2bf(h[tid]);
    else      ((float*)outv)[16384 + b * 64 + tid] = h[tid];
  }
}

// ---------- logits = rout @ out_w + out_b ----------
__global__ __launch_bounds__(256)
void k_logits(const int* __restrict__ flagp, const float* __restrict__ rout,
              const float* __restrict__ consts, void* __restrict__ outv) {
  __shared__ float W[512];
  __shared__ float Bv[8];
  const int isbf = *flagp;
  const int tid = threadIdx.x;
  for (int e = tid; e < 512; e += 256) W[e] = consts[480 + e];
  if (tid < 8) Bv[tid] = consts[992 + tid];
  __syncthreads();
  const int bt = blockIdx.x * 256 + tid;
  float acc[8];
  #pragma unroll
  for (int c = 0; c < 8; ++c) acc[c] = Bv[c];
  const f32x4* r = (const f32x4*)(rout + (size_t)bt * 64);
  #pragma unroll
  for (int q = 0; q < 16; ++q) {
    f32x4 v = r[q];
    #pragma unroll
    for (int u = 0; u < 4; ++u) {
      const float rv = v[u];
      const int i = 4 * q + u;
      #pragma unroll
      for (int c = 0; c < 8; ++c) acc[c] += rv * W[i * 8 + c];
    }
  }
  if (isbf) {
    u32 pk[4];
    #pragma unroll
    for (int c = 0; c < 4; ++c)
      pk[c] = (u32)f2bf(acc[2 * c]) | ((u32)f2bf(acc[2 * c + 1]) << 16);
    *(uint4*)((u16*)outv + (size_t)bt * 8) = *(const uint4*)pk;
  } else {
    float* o = (float*)outv + (size_t)bt * 8;
    *(f32x4*)o = f32x4{acc[0], acc[1], acc[2], acc[3]};
    *(f32x4*)(o + 4) = f32x4{acc[4], acc[5], acc[6], acc[7]};
  }
}

extern "C" void kernel_launch(void* const* d_in, const int* in_sizes, int n_in,
                              void* d_out, int out_size, void* d_ws, size_t ws_size,
                              hipStream_t stream) {
  const void* x   = d_in[0];
  const void* hx  = d_in[1];
  const void* w1  = d_in[2];
  const void* b1  = d_in[3];
  const void* w2  = d_in[4];
  const void* b2  = d_in[5];
  const void* bbw = d_in[6];
  const void* bbb = d_in[7];
  const void* f1w = d_in[8];
  const void* f1b = d_in[9];
  const void* f2w = d_in[10];
  const void* f2b = d_in[11];
  const void* taw = d_in[12];
  const void* tab = d_in[13];
  const void* tbw = d_in[14];
  const void* tbb = d_in[15];
  const void* oww = d_in[16];
  const void* obb = d_in[17];

  char* ws = (char*)d_ws;
  float* xbp   = (float*)(ws);
  u16*   feats = (u16*)(ws + 150994944);
  u16*   bbT   = (u16*)(ws + 218103808);
  u16*   HT    = (u16*)(ws + 222314496);
  u16*   w1p   = (u16*)(ws + 222380032);
  u16*   w2c   = (u16*)(ws + 222384128);
  float* xb    = (float*)(ws + 222449664);
  float* rout  = (float*)(ws + 223498240);
  float* consts= (float*)(ws + 224022528);
  int*   flag  = (int*)(ws + 224034816);

  k_prep_all<<<670, 256, 0, stream>>>((const u32*)bbw, b1, b2, bbb, f1b, f2b,
                                      tab, tbb, oww, obb, hx, w1, w2, bbw,
                                      f1w, f2w, taw, tbw,
                                      consts, w1p, w2c, bbT, HT, flag);
  k_convs<<<2048, 512, 0, stream>>>(flag, x, w1p, w2c, consts, feats);
  k_xb<<<dim3(32, 16), 256, 0, stream>>>(feats, bbT, xbp);
  k_xbsum<<<1024, 256, 0, stream>>>(xbp, xb);
  k_rec<<<32, 256, 0, stream>>>(flag, xb, bbT, HT, consts, rout, d_out);
  k_logits<<<8, 256, 0, stream>>>(flag, rout, consts, d_out);
}

// Round 14
// 383.142 us; speedup vs baseline: 1.5197x; 1.1030x over previous
//
#include <hip/hip_runtime.h>
#include <stdint.h>

// DoomLiquidNet: conv(3->32,k4s2p1) -> conv(32->64,k4s2p1) -> CfC core -> logits
// Inputs f32 (detected on device; bf16 fallback kept). Compute in bf16 MFMA.
//
// R20 = R14 k_convs (champion, 124us) + RESTRUCTURED k_rec.
//   R19 null result: (256,1) on old k_rec changed nothing (total 422.6 ===
//   R14's 421) -> k_rec's ~103us is STRUCTURAL, not spill: per step 4 waves
//   issue 64+128 scalar broadcast ds_read_b32 (~3700 cyc LDS pipe) + 3
//   barriers at 1 wave/SIMD. (R18's WRITE 520KB = exactly rout; no HBM spill
//   signature. Any scratch hides in L2, invisible to FETCH_SIZE.)
//   New k_rec (512 thr): h/bbv as f32x4 (b128 reads: P1 32, P2 128 vs
//   128+512 scalar); K-split dots + __shfl_xor combine (w1r[16]+w2r[64]=80
//   floats/thread -> no spill under any cap); P3 merged into P2 tail via
//   in-wave __shfl gather (wave w owns heads {g*64+w*8+j}) -> 2 barriers+
//   h-barrier per step, heads[] LDS gone. Est 3860 -> ~2300 cyc/step.
// R14: conv2 wave remap: ONE w2c fragment/kst x 8 MFMA -> k_convs 193->124us.
//
// ws layout:
//   xbp   : f32  [16][2048][128]     @ 0           16777216 B
//   feats : bf16 [2048][16384]       @ 150994944   67108864 B
//   bbT   : bf16 [128][16448]        @ 218103808    4210688 B
//   HT    : bf16 [256][128]          @ 222314496      65536 B
//   w1p   : bf16 [32][64]            @ 222380032       4096 B
//   w2c   : bf16 [64][512]           @ 222384128      65536 B
//   xb    : f32  [2048][128]         @ 222449664    1048576 B
//   rout  : f32  [2048][64]          @ 223498240     524288 B
//   consts: f32  [3048]              @ 224022528      12288 B
//   flag  : int                      @ 224034816          4 B

typedef unsigned short u16;
typedef unsigned int u32;

typedef float f32x4 __attribute__((ext_vector_type(4)));
typedef short s16x8 __attribute__((ext_vector_type(8)));
typedef __bf16 b16x8 __attribute__((ext_vector_type(8)));

template <typename V>
__device__ inline auto mfma_sel(V a, V b, f32x4 c, int)
    -> decltype(__builtin_amdgcn_mfma_f32_16x16x32_bf16(a, b, c, 0, 0, 0)) {
  return __builtin_amdgcn_mfma_f32_16x16x32_bf16(a, b, c, 0, 0, 0);
}
template <typename V>
__device__ inline f32x4 mfma_sel(V a, V b, f32x4 c, long) {
  union UU { V s; b16x8 b; };
  UU ua; ua.s = a;
  UU ub; ub.s = b;
  return __builtin_amdgcn_mfma_f32_16x16x32_bf16(ua.b, ub.b, c, 0, 0, 0);
}
__device__ inline f32x4 mfma16x16x32(s16x8 a, s16x8 b, f32x4 c) {
  return mfma_sel(a, b, c, 0);
}

__device__ inline float bf2f(u16 v) {
  union { u32 i; float f; } x; x.i = ((u32)v) << 16; return x.f;
}
__device__ inline u16 f2bf(float f) {  // round-to-nearest-even
  union { float f; u32 i; } x; x.f = f;
  u32 i = x.i;
  i += 0x7fffu + ((i >> 16) & 1u);
  return (u16)(i >> 16);
}
__device__ inline void bf2x2(u32 u, float& lo, float& hi) {
  union { u32 i; float f; } a, b;
  a.i = u << 16; b.i = u & 0xffff0000u;
  lo = a.f; hi = b.f;
}
__device__ inline float ldf(int isbf, const void* p, size_t i) {
  return isbf ? bf2f(((const u16*)p)[i]) : ((const float*)p)[i];
}
__device__ inline u16 ldb(int isbf, const void* p, size_t i) {
  return isbf ? ((const u16*)p)[i] : f2bf(((const float*)p)[i]);
}
__device__ inline float fast_tanh(float x) {
  float ax = fabsf(x);
  float e = __expf(2.0f * ax);
  float t = 1.0f - 2.0f / (e + 1.0f);
  return copysignf(t, x);
}

// ---------- fused prep: detect + consts + w1p + w2c + bbT + HT ----------
__global__ __launch_bounds__(256)
void k_prep_all(const u32* __restrict__ bwords,
                const void* b1, const void* b2, const void* bbb,
                const void* f1b, const void* f2b, const void* tab,
                const void* tbb, const void* oww, const void* obb,
                const void* hx, const void* w1, const void* w2,
                const void* bw, const void* f1w, const void* f2w,
                const void* taw, const void* tbw,
                float* __restrict__ consts, u16* __restrict__ w1p,
                u16* __restrict__ w2c, u16* __restrict__ bbT,
                u16* __restrict__ HT, int* __restrict__ flag) {
  __shared__ u16 t[64][65];
  const int tid = threadIdx.x;
  const int b = blockIdx.x;
  const u32 wd = bwords[tid & 63];
  const u32 ex = (wd >> 7) & 0xFFu;
  unsigned long long m = __ballot(ex >= 100u && ex <= 126u);
  const int isbf = (__popcll(m) >= 32) ? 1 : 0;
  if (b == 0 && tid == 0) *flag = isbf;

  if (b < 12) {
    const int e = b * 256 + tid;
    if (e >= 3048) return;
    float v;
    if (e < 32)        v = ldf(isbf, b1, e);
    else if (e < 96)   v = ldf(isbf, b2, e - 32);
    else if (e < 224)  v = ldf(isbf, bbb, e - 96);
    else if (e < 288)  v = ldf(isbf, f1b, e - 224);
    else if (e < 352)  v = ldf(isbf, f2b, e - 288);
    else if (e < 416)  v = ldf(isbf, tab, e - 352);
    else if (e < 480)  v = ldf(isbf, tbb, e - 416);
    else if (e < 992)  v = ldf(isbf, oww, e - 480);
    else if (e < 1000) v = ldf(isbf, obb, e - 992);
    else               v = ldf(isbf, hx, e - 1000);
    consts[e] = v;
  } else if (b < 20) {
    const int e = (b - 12) * 256 + tid;
    const int k = e & 63, co = e >> 6;
    w1p[e] = (k < 48) ? ldb(isbf, w1, co * 48 + k) : (u16)0;
  } else if (b < 148) {
    const int e = (b - 20) * 256 + tid;
    w2c[e] = ldb(isbf, w2, e);
  } else if (b < 662) {
    const int idx = b - 148;
    const int k0 = (idx >> 1) * 64, j0 = (idx & 1) * 64;
    #pragma unroll
    for (int i = 0; i < 16; ++i) {
      int e = tid + 256 * i;
      int kl = e >> 6, jl = e & 63;
      t[kl][jl] = ldb(isbf, bw, (size_t)(k0 + kl) * 128 + j0 + jl);
    }
    __syncthreads();
    #pragma unroll
    for (int i = 0; i < 16; ++i) {
      int e = tid + 256 * i;
      int jl = e >> 6, kl = e & 63;
      bbT[(size_t)(j0 + jl) * 16448 + k0 + kl] = t[kl][jl];
    }
  } else {
    const int idx = b - 662;
    const int h = idx >> 1, i0 = (idx & 1) * 64;
    const void* W = (h == 0) ? f1w : (h == 1) ? f2w : (h == 2) ? taw : tbw;
    #pragma unroll
    for (int i = 0; i < 16; ++i) {
      int e = tid + 256 * i;
      int il = e >> 6, cl = e & 63;
      t[il][cl] = ldb(isbf, W, (i0 + il) * 64 + cl);
    }
    __syncthreads();
    #pragma unroll
    for (int i = 0; i < 16; ++i) {
      int e = tid + 256 * i;
      int cl = e >> 6, il = e & 63;
      HT[(h * 64 + cl) * 128 + i0 + il] = t[il][cl];
    }
  }
}

// ---------- fused conv1+conv2: one image per block (R14 structure) ----------
// LDS u32 map:
//   XS   @ 0     : 3 planes x 66 rows x 34 u32 (shifted-pair, rows 0/65 = 0)
//   ZS   @ 6732  : 68 u32 zeros (conv1 K-pad plane reads)
//   A1H  @ 6800  : 16 planes x 34 rows x 18 u32 (shifted-pair, rows 0/33 = 0)
//   total 16592 u32 = 66368 B  -> 2 blocks/CU
__global__ __launch_bounds__(512, 4)
void k_convs(const int* __restrict__ flagp, const void* __restrict__ x,
             const u16* __restrict__ w1p, const u16* __restrict__ w2c,
             const float* __restrict__ consts, u16* __restrict__ feats) {
  __shared__ u32 lx[16592];
  const int isbf = *flagp;
  const int n = blockIdx.x;
  const int tid = threadIdx.x;
  const int wv = tid >> 6, lane = tid & 63, quad = lane >> 4, l15 = lane & 15;

  // zero: xs border rows + zero strip + whole a1h (disjoint from staging)
  for (int e = tid; e < 10064; e += 512) {
    int idx;
    if (e < 204) {
      const int pl = e / 68;
      const int rem = e - pl * 68;
      const int r = rem / 34;
      idx = pl * 2244 + r * (65 * 34) + (rem - r * 34);
    } else if (e < 272) {
      idx = 6732 + (e - 204);
    } else {
      idx = 6800 + (e - 272);
    }
    lx[idx] = 0u;
  }
  // stage x -> XS (interior rows 1..64), shifted-pair bf16
  for (int e = tid; e < 3072; e += 512) {
    const int ci = e >> 10;
    const int rr = (e >> 4) & 63;
    const int tt = e & 15;
    u32* dst = &lx[(ci * 66 + rr + 1) * 34];
    if (!isbf) {
      const float* src = (const float*)x + (((size_t)n * 3 + ci) * 64 + rr) * 64 + 4 * tt;
      const f32x4 v = *(const f32x4*)src;
      const float pv = tt ? src[-1] : 0.f;
      dst[2 * tt]     = (u32)f2bf(pv)   | (((u32)f2bf(v[0])) << 16);
      dst[2 * tt + 1] = (u32)f2bf(v[1]) | (((u32)f2bf(v[2])) << 16);
      if (tt == 15) { dst[32] = (u32)f2bf(v[3]); dst[33] = 0u; }
    } else {
      const u16* src = (const u16*)x + (((size_t)n * 3 + ci) * 64 + rr) * 64 + 4 * tt;
      const u16 pv = tt ? src[-1] : (u16)0;
      dst[2 * tt]     = (u32)pv | (((u32)src[0]) << 16);
      dst[2 * tt + 1] = (u32)src[1] | (((u32)src[2]) << 16);
      if (tt == 15) { dst[32] = (u32)src[3]; dst[33] = 0u; }
    }
  }
  __syncthreads();

  f32x4 acc2[8];
  #pragma unroll
  for (int rr = 0; rr < 8; ++rr) acc2[rr] = f32x4{0.f, 0.f, 0.f, 0.f};

  const int khb = (quad & 1) * 2;
  const int cih = quad >> 1;
  const int mt = wv & 3;    // conv2: co-group
  const int og = wv >> 2;   // conv2: oh-octet (oh = og*8 + rr)
  u16* lp = (u16*)lx;

  #pragma unroll
  for (int h = 0; h < 2; ++h) {
    // ---- conv1 half: co = h*16 .. h*16+15 -> A1H ----
    const s16x8 af0 = *(const s16x8*)(w1p + (h * 16 + l15) * 64 + quad * 8);
    const s16x8 af1 = *(const s16x8*)(w1p + (h * 16 + l15) * 64 + 32 + quad * 8);
    #pragma unroll
    for (int i = 0; i < 8; ++i) {
      const int nt = wv * 8 + i;
      const int oh = nt >> 1;
      const int ob = (nt & 1) * 16;
      f32x4 a1acc = f32x4{0.f, 0.f, 0.f, 0.f};
      {
        const int base = (cih * 66 + 2 * oh + khb) * 34 + ob + l15;
        union { u32 u[4]; s16x8 v; } bf;
        bf.u[0] = lx[base];
        bf.u[1] = lx[base + 1];
        bf.u[2] = lx[base + 34];
        bf.u[3] = lx[base + 35];
        a1acc = mfma16x16x32(af0, bf.v, a1acc);
      }
      {
        const int ci1 = 2 + cih;  // 2 or 3 (3 = K-pad -> zero strip)
        const int base = (ci1 < 3) ? ((ci1 * 66 + 2 * oh + khb) * 34 + ob + l15)
                                   : (6732 + ob + l15);
        union { u32 u[4]; s16x8 v; } bf;
        bf.u[0] = lx[base];
        bf.u[1] = lx[base + 1];
        bf.u[2] = lx[base + 34];
        bf.u[3] = lx[base + 35];
        a1acc = mfma16x16x32(af1, bf.v, a1acc);
      }
      #pragma unroll
      for (int r = 0; r < 4; ++r) {
        const int co = quad * 4 + r;
        float v = a1acc[r] + consts[h * 16 + co];
        v = v > 0.f ? v : 0.f;
        lp[(6800 + (co * 34 + oh + 1) * 18) * 2 + ob + l15 + 1] = f2bf(v);
      }
    }
    __syncthreads();  // a1 half ready
    // ---- conv2 K-half: planes 16h..16h+15 ----
    // wave remap: ONE w2c fragment per kst (mt fixed), 8 MFMA vs a1 rows.
    #pragma unroll
    for (int kst = 0; kst < 8; ++kst) {
      const int kglob = h * 8 + kst;
      const s16x8 afr =
          *(const s16x8*)(w2c + (mt * 16 + l15) * 512 + kglob * 32 + quad * 8);
      const int ci = kst * 2 + cih;
      #pragma unroll
      for (int rr = 0; rr < 8; ++rr) {
        const int row1 = 2 * (og * 8 + rr) + khb;
        const int base = 6800 + (ci * 34 + row1) * 18 + l15;
        union { u32 u[4]; s16x8 v; } bf;
        bf.u[0] = lx[base];
        bf.u[1] = lx[base + 1];
        bf.u[2] = lx[base + 18];
        bf.u[3] = lx[base + 19];
        acc2[rr] = mfma16x16x32(afr, bf.v, acc2[rr]);
      }
    }
    if (h == 0) __syncthreads();  // conv2 h0 done reading before conv1 h1 writes
  }
  // ---- epilogue: feats ----
  #pragma unroll
  for (int rr = 0; rr < 8; ++rr) {
    const int oh = og * 8 + rr;
    #pragma unroll
    for (int r = 0; r < 4; ++r) {
      const int co = mt * 16 + quad * 4 + r;
      const float bias = consts[32 + co];
      float v = acc2[rr][r] + bias;
      v = v > 0.f ? v : 0.f;
      feats[(size_t)n * 16384 + co * 256 + oh * 16 + l15] = f2bf(v);
    }
  }
}

// ---------- xb partials: feats @ bb_w[:16384], split-K=16, NO atomics ------
__global__ __launch_bounds__(256)
void k_xb(const u16* __restrict__ feats, const u16* __restrict__ bbT,
          float* __restrict__ xbp) {
  const int m0 = blockIdx.x * 64;
  const int kc = blockIdx.y;
  const int kc0 = kc * 1024;
  const int tid = threadIdx.x;
  const int w = tid >> 6, lane = tid & 63, quad = lane >> 4, l15 = lane & 15;
  f32x4 acc[4][2];
  #pragma unroll
  for (int mt = 0; mt < 4; ++mt)
    #pragma unroll
    for (int i = 0; i < 2; ++i) acc[mt][i] = f32x4{0.f, 0.f, 0.f, 0.f};
  #pragma unroll 4
  for (int kst = 0; kst < 32; ++kst) {
    const int k = kc0 + kst * 32 + quad * 8;
    s16x8 afrag[4], bfrag[2];
    #pragma unroll
    for (int mt = 0; mt < 4; ++mt)
      afrag[mt] = *(const s16x8*)(feats + (size_t)(m0 + mt * 16 + l15) * 16384 + k);
    #pragma unroll
    for (int i = 0; i < 2; ++i)
      bfrag[i] = *(const s16x8*)(bbT + (size_t)((w * 2 + i) * 16 + l15) * 16448 + k);
    #pragma unroll
    for (int mt = 0; mt < 4; ++mt)
      #pragma unroll
      for (int i = 0; i < 2; ++i)
        acc[mt][i] = mfma16x16x32(afrag[mt], bfrag[i], acc[mt][i]);
  }
  float* dst = xbp + (size_t)kc * 262144;
  #pragma unroll
  for (int mt = 0; mt < 4; ++mt)
    #pragma unroll
    for (int i = 0; i < 2; ++i) {
      const int j = (w * 2 + i) * 16 + l15;
      #pragma unroll
      for (int r = 0; r < 4; ++r) {
        const int m = m0 + mt * 16 + quad * 4 + r;
        dst[m * 128 + j] = acc[mt][i][r];
      }
    }
}

// ---------- reduce split-K partials -> xb ----------
__global__ __launch_bounds__(256)
void k_xbsum(const float* __restrict__ xbp, float* __restrict__ xb) {
  const int e = blockIdx.x * 256 + threadIdx.x;
  float s = 0.f;
  #pragma unroll
  for (int kc = 0; kc < 16; ++kc) s += xbp[(size_t)kc * 262144 + e];
  xb[e] = s;
}

// ---------- CfC recurrence (R20): 512 thr, K-split + shfl combine ----------
// Per wave w (8 waves), lane l:
//   P1: output jo = w*16 + (l&15), K-quarter kh1 = l>>4 (16 h-values);
//       w1r[16] in regs; combine via shfl_xor(16)+shfl_xor(32);
//       lanes l<16 apply bias+lecun_tanh -> bbv[jo].
//   P2: output jo2 = g*64 + w*8 + (l&7), g=(l>>3)&3, K-half kh2 = l>>5;
//       w2r[64] in regs; combine via shfl_xor(32); + hbias;
//       in-wave shfl gather of 4 groups -> lanes l<8 compute h_new for
//       unit u = w*8 + l (P3 merged; no heads[] LDS, no 3rd phase barrier).
// LDS reads vectorized f32x4: P1 4/thread, P2 16/thread.
// Regs: w2r[64]+w1r[16] = 80 floats + temps (~100) - no spill.
__global__ __launch_bounds__(512, 1)
void k_rec(const int* __restrict__ flagp, const float* __restrict__ xb,
           const u16* __restrict__ bbT, const u16* __restrict__ HT,
           const float* __restrict__ consts, float* __restrict__ rout,
           void* __restrict__ outv) {
  __shared__ float xbl[64 * 128];
  __shared__ f32x4 h4[16];
  __shared__ f32x4 bb4[32];
  const int isbf = *flagp;
  const int b = blockIdx.x;
  const int tid = threadIdx.x;
  const int w = tid >> 6;
  const int l = tid & 63;
  float* h = (float*)h4;
  float* bbv = (float*)bb4;

  // stage xb row
  {
    const float* src = xb + (size_t)b * 64 * 128;
    #pragma unroll
    for (int q = 0; q < 16; ++q) xbl[q * 512 + tid] = src[q * 512 + tid];
  }
  // P1 weights: output jo, K-quarter kh1
  const int jo = w * 16 + (l & 15);
  const int kh1 = l >> 4;
  float w1r[16];
  {
    const u32* src = (const u32*)(bbT + (size_t)jo * 16448 + 16384 + kh1 * 16);
    #pragma unroll
    for (int q = 0; q < 8; ++q) bf2x2(src[q], w1r[2 * q], w1r[2 * q + 1]);
  }
  // P2 weights: output jo2, K-half kh2
  const int g = (l >> 3) & 3;
  const int u8 = l & 7;
  const int jo2 = g * 64 + w * 8 + u8;
  const int kh2 = l >> 5;
  float w2r[64];
  {
    const u32* src = (const u32*)(HT + jo2 * 128 + kh2 * 64);
    #pragma unroll
    for (int q = 0; q < 32; ++q) bf2x2(src[q], w2r[2 * q], w2r[2 * q + 1]);
  }
  const float bbias = consts[96 + jo];
  const float hbias = consts[224 + jo2];
  if (tid < 64) h[tid] = consts[1000 + b * 64 + tid];
  __syncthreads();

  for (int t = 0; t < 64; ++t) {
    // ---- P1: bbv = lecun_tanh(h @ W1h + xb_t + bb_b) ----
    float p = 0.f;
    #pragma unroll
    for (int q = 0; q < 4; ++q) {
      const f32x4 hv = h4[kh1 * 4 + q];
      p += hv[0] * w1r[4 * q + 0];
      p += hv[1] * w1r[4 * q + 1];
      p += hv[2] * w1r[4 * q + 2];
      p += hv[3] * w1r[4 * q + 3];
    }
    p += __shfl_xor(p, 16);
    p += __shfl_xor(p, 32);
    if (l < 16) {
      const float s = p + xbl[t * 128 + jo] + bbias;
      bbv[jo] = 1.7159f * fast_tanh(0.666f * s);
    }
    __syncthreads();
    // ---- P2 + P3: heads -> h_new (in-wave) ----
    float p2 = 0.f;
    #pragma unroll
    for (int q = 0; q < 16; ++q) {
      const f32x4 bv = bb4[kh2 * 16 + q];
      p2 += bv[0] * w2r[4 * q + 0];
      p2 += bv[1] * w2r[4 * q + 1];
      p2 += bv[2] * w2r[4 * q + 2];
      p2 += bv[3] * w2r[4 * q + 3];
    }
    p2 += __shfl_xor(p2, 32);
    p2 += hbias;  // lanes l and l^32 both hold the total for jo2
    const float v0 = __shfl(p2, u8);        // g=0: ff1 head
    const float v1 = __shfl(p2, 8 + u8);    // g=1: ff2 head
    const float v2 = __shfl(p2, 16 + u8);   // g=2: ta head
    const float v3 = __shfl(p2, 24 + u8);   // g=3: tb head
    if (l < 8) {
      const float ff1 = fast_tanh(v0);
      const float ff2 = fast_tanh(v1);
      const float ti = 1.f / (1.f + __expf(-(v2 + v3)));
      const float hn = ff1 * (1.f - ti) + ti * ff2;
      const int unit = w * 8 + l;
      h[unit] = hn;
      rout[((size_t)b * 64 + t) * 64 + unit] = hn;
    }
    __syncthreads();
  }
  if (tid < 64) {
    if (isbf) ((u16*)outv)[16384 + b * 64 + tid] = f2bf(h[tid]);
    else      ((float*)outv)[16384 + b * 64 + tid] = h[tid];
  }
}

// ---------- logits = rout @ out_w + out_b ----------
__global__ __launch_bounds__(256)
void k_logits(const int* __restrict__ flagp, const float* __restrict__ rout,
              const float* __restrict__ consts, void* __restrict__ outv) {
  __shared__ float W[512];
  __shared__ float Bv[8];
  const int isbf = *flagp;
  const int tid = threadIdx.x;
  for (int e = tid; e < 512; e += 256) W[e] = consts[480 + e];
  if (tid < 8) Bv[tid] = consts[992 + tid];
  __syncthreads();
  const int bt = blockIdx.x * 256 + tid;
  float acc[8];
  #pragma unroll
  for (int c = 0; c < 8; ++c) acc[c] = Bv[c];
  const f32x4* r = (const f32x4*)(rout + (size_t)bt * 64);
  #pragma unroll
  for (int q = 0; q < 16; ++q) {
    f32x4 v = r[q];
    #pragma unroll
    for (int u = 0; u < 4; ++u) {
      const float rv = v[u];
      const int i = 4 * q + u;
      #pragma unroll
      for (int c = 0; c < 8; ++c) acc[c] += rv * W[i * 8 + c];
    }
  }
  if (isbf) {
    u32 pk[4];
    #pragma unroll
    for (int c = 0; c < 4; ++c)
      pk[c] = (u32)f2bf(acc[2 * c]) | ((u32)f2bf(acc[2 * c + 1]) << 16);
    *(uint4*)((u16*)outv + (size_t)bt * 8) = *(const uint4*)pk;
  } else {
    float* o = (float*)outv + (size_t)bt * 8;
    *(f32x4*)o = f32x4{acc[0], acc[1], acc[2], acc[3]};
    *(f32x4*)(o + 4) = f32x4{acc[4], acc[5], acc[6], acc[7]};
  }
}

extern "C" void kernel_launch(void* const* d_in, const int* in_sizes, int n_in,
                              void* d_out, int out_size, void* d_ws, size_t ws_size,
                              hipStream_t stream) {
  const void* x   = d_in[0];
  const void* hx  = d_in[1];
  const void* w1  = d_in[2];
  const void* b1  = d_in[3];
  const void* w2  = d_in[4];
  const void* b2  = d_in[5];
  const void* bbw = d_in[6];
  const void* bbb = d_in[7];
  const void* f1w = d_in[8];
  const void* f1b = d_in[9];
  const void* f2w = d_in[10];
  const void* f2b = d_in[11];
  const void* taw = d_in[12];
  const void* tab = d_in[13];
  const void* tbw = d_in[14];
  const void* tbb = d_in[15];
  const void* oww = d_in[16];
  const void* obb = d_in[17];

  char* ws = (char*)d_ws;
  float* xbp   = (float*)(ws);
  u16*   feats = (u16*)(ws + 150994944);
  u16*   bbT   = (u16*)(ws + 218103808);
  u16*   HT    = (u16*)(ws + 222314496);
  u16*   w1p   = (u16*)(ws + 222380032);
  u16*   w2c   = (u16*)(ws + 222384128);
  float* xb    = (float*)(ws + 222449664);
  float* rout  = (float*)(ws + 223498240);
  float* consts= (float*)(ws + 224022528);
  int*   flag  = (int*)(ws + 224034816);

  k_prep_all<<<670, 256, 0, stream>>>((const u32*)bbw, b1, b2, bbb, f1b, f2b,
                                      tab, tbb, oww, obb, hx, w1, w2, bbw,
                                      f1w, f2w, taw, tbw,
                                      consts, w1p, w2c, bbT, HT, flag);
  k_convs<<<2048, 512, 0, stream>>>(flag, x, w1p, w2c, consts, feats);
  k_xb<<<dim3(32, 16), 256, 0, stream>>>(feats, bbT, xbp);
  k_xbsum<<<1024, 256, 0, stream>>>(xbp, xb);
  k_rec<<<32, 512, 0, stream>>>(flag, xb, bbT, HT, consts, rout, d_out);
  k_logits<<<8, 256, 0, stream>>>(flag, rout, consts, d_out);
}